// Round 10
// baseline (15792.340 us; speedup 1.0000x reference)
//
#include <hip/hip_runtime.h>

// BiLSTM-CRF forward on MI355X.
//   bias:    bias sums.
//   wtrans:  LDS-tiled transpose of W_ih to [k][row].
//   wquant:  per-row int8 quantization of W_hh, PERMUTED k-packing: dword j of a
//            row packs W[row][{j, j+64, j+128, j+192}] -> h LDS dword u packs
//            units {u, u+64, u+128, u+192} (publisher writes ONE b32).
//   gin:     embedding gather + input projection -> gin[t][rp] (rp = u*4+gate).
//   lstm:    2 blocks x 256 threads (one CU per direction), 4 waves (1/SIMD,
//            512-reg budget). Thread t: rows rp = tid+256m (m=0..3, same gate
//            g=tid&3, units u0+64m). 256 w dwords in regs. Per step: 16
//            ds_read_b128 broadcast -> h4[16], 256 sdot4 (8 indep chains),
//            4 acts, 16 DPP quad gathers, 4 cell updates, 1 packed ds_write_b32
//            + 4 hcomp stores (publishers), one barrier. Unroll-2 with
//            alternating gin register buffers (distance-2 prefetch, no copies).
//   feats:   [hf,hr] @ w_out^T + b_out.
//   viterbi: register-resident single-wave DP (proven) + 3-phase backtrace.

#define SEQ  8192
#define EMBD 256
#define HD   256
#define G4   1024
#define NEGV -10000.0f

#if __has_builtin(__builtin_amdgcn_sdot4)
__device__ __forceinline__ int SDOT4(unsigned a, unsigned b, int c) {
    return __builtin_amdgcn_sdot4((int)a, (int)b, c, false);
}
#else
__device__ __forceinline__ int SDOT4(unsigned a, unsigned b, int c) {
#pragma unroll
    for (int i = 0; i < 4; ++i) {
        int ai = (int)(a << (24 - 8 * i)) >> 24;
        int bi = (int)(b << (24 - 8 * i)) >> 24;
        c += ai * bi;
    }
    return c;
}
#endif

// DPP quad_perm broadcast (VALU pipe): every lane gets its quad's position-K value
template <int CTRL>
__device__ __forceinline__ float dpp_bcast(float x) {
    return __int_as_float(
        __builtin_amdgcn_mov_dpp(__float_as_int(x), CTRL, 0xf, 0xf, true));
}

// ---------------------------------------------------------------- bias sums
__global__ void bias_kernel(const float* __restrict__ b_ih_f, const float* __restrict__ b_hh_f,
                            const float* __restrict__ b_ih_r, const float* __restrict__ b_hh_r,
                            float* __restrict__ bs_f, float* __restrict__ bs_r) {
    int i = threadIdx.x;
#pragma unroll
    for (int m = 0; m < 4; ++m) {
        int row = i + 256 * m;
        bs_f[row] = b_ih_f[row] + b_hh_f[row];
        bs_r[row] = b_ih_r[row] + b_hh_r[row];
    }
}

// ---------------------------------------------------------------- W_ih transpose (tiled)
__global__ __launch_bounds__(256) void wtrans_kernel(
    const float* __restrict__ w_ih_f, const float* __restrict__ w_ih_r,
    float* __restrict__ wt_f, float* __restrict__ wt_r) {
    __shared__ float tile[32][257];
    int mat = blockIdx.x & 1;
    int r0  = (blockIdx.x >> 1) << 5;          // 0,32,...,992
    const float* src = mat ? w_ih_r : w_ih_f;
    float*       dst = mat ? wt_r   : wt_f;
    int tid = threadIdx.x;
    for (int r = 0; r < 32; ++r)
        tile[r][tid] = src[(size_t)(r0 + r) * EMBD + tid];
    __syncthreads();
    int row = tid & 31, kq = tid >> 5;
    for (int kb = 0; kb < EMBD; kb += 8) {
        int k = kb + kq;
        dst[(size_t)k * G4 + r0 + row] = tile[row][k];
    }
}

// ---------------------------------------------------------------- W_hh int8 quantization
// 2048 blocks x 64 threads: dir=b>>10, permuted row rp=b&1023 (rp=u*4+gate,
// original row = gate*256+u). PERMUTED k-packing: wq[dir][j][rp] packs
// W[row][{j, j+64, j+128, j+192}] in bytes 0..3 (matches permuted h layout).
__global__ __launch_bounds__(64) void wquant_kernel(
    const float* __restrict__ w_hh_f, const float* __restrict__ w_hh_r,
    unsigned* __restrict__ wq, float* __restrict__ fac)
{
    int b = blockIdx.x;
    int dir = b >> 10, rp = b & 1023;
    int row = (rp & 3) * 256 + (rp >> 2);
    int l = threadIdx.x;                       // permuted kdword 0..63
    const float* Wr = (dir ? w_hh_r : w_hh_f) + (size_t)row * HD;
    float v0 = Wr[l], v1 = Wr[l + 64], v2 = Wr[l + 128], v3 = Wr[l + 192];
    float m = fmaxf(fmaxf(fabsf(v0), fabsf(v1)), fmaxf(fabsf(v2), fabsf(v3)));
#pragma unroll
    for (int off = 1; off < 64; off <<= 1) m = fmaxf(m, __shfl_xor(m, off));
    m = fmaxf(m, 1e-20f);
    float inv = 127.f / m;
    int q0 = (int)rintf(v0 * inv), q1 = (int)rintf(v1 * inv);
    int q2 = (int)rintf(v2 * inv), q3 = (int)rintf(v3 * inv);
    unsigned pk = (unsigned)(q0 & 0xff) | ((unsigned)(q1 & 0xff) << 8) |
                  ((unsigned)(q2 & 0xff) << 16) | ((unsigned)(q3 & 0xff) << 24);
    wq[(size_t)dir * 65536 + (size_t)l * 1024 + rp] = pk;
    if (l == 0) fac[dir * 1024 + rp] = m / (127.f * 127.f);   // dequant scale
}

// ---------------------------------------------------------------- input projection
// writes gin[t][rp] with rp = u*4+gate (bias included)
__global__ __launch_bounds__(256) void gin_kernel(
    const int* __restrict__ sentence, const float* __restrict__ emb,
    const float* __restrict__ wt_f, const float* __restrict__ wt_r,
    const float* __restrict__ bs_f, const float* __restrict__ bs_r,
    float* __restrict__ gin_f, float* __restrict__ gin_r)
{
    __shared__ float x_lds[32][EMBD];
    __shared__ int   sid_lds[32];
    int t0  = blockIdx.x * 32;
    int tid = threadIdx.x;
    if (tid < 32) sid_lds[tid] = sentence[t0 + tid];
    __syncthreads();
    for (int i = 0; i < 32; ++i)
        x_lds[i][tid] = emb[(size_t)sid_lds[i] * EMBD + tid];
    __syncthreads();

    float bsv[8];
#pragma unroll
    for (int m = 0; m < 4; ++m) bsv[m]     = bs_f[tid + 256 * m];
#pragma unroll
    for (int m = 0; m < 4; ++m) bsv[4 + m] = bs_r[tid + 256 * m];

    for (int tsub = 0; tsub < 4; ++tsub) {
        float acc[8][8];
#pragma unroll
        for (int m = 0; m < 8; ++m)
#pragma unroll
            for (int j = 0; j < 8; ++j) acc[m][j] = bsv[m];

        for (int k = 0; k < EMBD; ++k) {
            float xv[8];
#pragma unroll
            for (int j = 0; j < 8; ++j) xv[j] = x_lds[tsub * 8 + j][k];
#pragma unroll
            for (int m = 0; m < 8; ++m) {
                float wv = (m < 4) ? wt_f[(size_t)k * G4 + tid + 256 * m]
                                   : wt_r[(size_t)k * G4 + tid + 256 * (m - 4)];
#pragma unroll
                for (int j = 0; j < 8; ++j) acc[m][j] = fmaf(wv, xv[j], acc[m][j]);
            }
        }
#pragma unroll
        for (int m = 0; m < 8; ++m) {
            int rp = tid * 4 + (m & 3);        // u = tid, gate = m&3
#pragma unroll
            for (int j = 0; j < 8; ++j) {
                int t = t0 + tsub * 8 + j;
                if (m < 4) gin_f[(size_t)t * G4 + rp] = acc[m][j];
                else       gin_r[(size_t)(SEQ - 1 - t) * G4 + rp] = acc[m][j];
            }
        }
    }
}

// ---------------------------------------------------------------- single-CU LSTM per direction
// 2 blocks x 256 threads (4 waves, 1/SIMD). Thread t: rows rp = tid+256m
// (units u0+64m, gate g=tid&3). 256 w dwords in regs (512-reg budget).
__global__ __launch_bounds__(256, 1) void lstm_kernel(
    const unsigned* __restrict__ wq, const float* __restrict__ fac,
    const float* __restrict__ gin_f, const float* __restrict__ gin_r,
    float* __restrict__ hcomp_f, float* __restrict__ hcomp_r)
{
    int dir = blockIdx.x;
    const float* gin   = dir ? gin_r   : gin_f;
    float*       hcomp = dir ? hcomp_r : hcomp_f;
    int tid = threadIdx.x;
    int g   = tid & 3;
    int u0  = tid >> 2;                        // 0..63
    bool q0 = (g == 0);

    unsigned w0[64], w1[64], w2[64], w3[64];
    {
        const unsigned* base = wq + (size_t)dir * 65536;
#pragma unroll
        for (int j = 0; j < 64; ++j) {
            w0[j] = base[(size_t)j * 1024 + tid];
            w1[j] = base[(size_t)j * 1024 + tid + 256];
            w2[j] = base[(size_t)j * 1024 + tid + 512];
            w3[j] = base[(size_t)j * 1024 + tid + 768];
        }
    }
    float fc0 = fac[dir * 1024 + tid];
    float fc1 = fac[dir * 1024 + tid + 256];
    float fc2 = fac[dir * 1024 + tid + 512];
    float fc3 = fac[dir * 1024 + tid + 768];

    __shared__ unsigned hq[2][64];             // permuted int8 h, double-buffered
    if (tid < 128) ((unsigned*)hq)[tid] = 0u;  // h(0) = 0 (both buffers)

    // uniform per-gate activation: sigmoid (a=1,b=-1,c=0); tanh=2*sigm(2x)-1
    float aa = (g == 2) ? 2.f : 1.f;
    float bb = (g == 2) ? -2.f : -1.f;
    float cc = (g == 2) ? -1.f : 0.f;
    float c0 = 0.f, c1 = 0.f, c2 = 0.f, c3 = 0.f;

    float ga0 = gin[tid],      ga1 = gin[tid + 256];
    float ga2 = gin[tid + 512], ga3 = gin[tid + 768];
    float gb0 = gin[G4 + tid],      gb1 = gin[G4 + tid + 256];
    float gb2 = gin[G4 + tid + 512], gb3 = gin[G4 + tid + 768];
    __syncthreads();

#define LSTM_STEP(T, V0, V1, V2, V3)                                           \
    {                                                                          \
        float gv0 = V0, gv1 = V1, gv2 = V2, gv3 = V3;                          \
        size_t pf = (size_t)(((T) + 2 < SEQ) ? (T) + 2 : (SEQ - 1)) * G4;      \
        V0 = gin[pf + tid];        V1 = gin[pf + tid + 256];                   \
        V2 = gin[pf + tid + 512];  V3 = gin[pf + tid + 768];                   \
        const uint4* hb = reinterpret_cast<const uint4*>(hq[(T) & 1]);         \
        uint4 h4[16];                                                          \
        _Pragma("unroll")                                                      \
        for (int j = 0; j < 16; ++j) h4[j] = hb[j];                            \
        int s0a = 0, s0b = 0, s1a = 0, s1b = 0;                                \
        int s2a = 0, s2b = 0, s3a = 0, s3b = 0;                                \
        _Pragma("unroll")                                                      \
        for (int j = 0; j < 16; ++j) {                                         \
            s0a = SDOT4(w0[4 * j + 0], h4[j].x, s0a);                          \
            s0b = SDOT4(w0[4 * j + 1], h4[j].y, s0b);                          \
            s1a = SDOT4(w1[4 * j + 0], h4[j].x, s1a);                          \
            s1b = SDOT4(w1[4 * j + 1], h4[j].y, s1b);                          \
            s2a = SDOT4(w2[4 * j + 0], h4[j].x, s2a);                          \
            s2b = SDOT4(w2[4 * j + 1], h4[j].y, s2b);                          \
            s3a = SDOT4(w3[4 * j + 0], h4[j].x, s3a);                          \
            s3b = SDOT4(w3[4 * j + 1], h4[j].y, s3b);                          \
            s0a = SDOT4(w0[4 * j + 2], h4[j].z, s0a);                          \
            s0b = SDOT4(w0[4 * j + 3], h4[j].w, s0b);                          \
            s1a = SDOT4(w1[4 * j + 2], h4[j].z, s1a);                          \
            s1b = SDOT4(w1[4 * j + 3], h4[j].w, s1b);                          \
            s2a = SDOT4(w2[4 * j + 2], h4[j].z, s2a);                          \
            s2b = SDOT4(w2[4 * j + 3], h4[j].w, s2b);                          \
            s3a = SDOT4(w3[4 * j + 2], h4[j].z, s3a);                          \
            s3b = SDOT4(w3[4 * j + 3], h4[j].w, s3b);                          \
        }                                                                      \
        float p0 = fmaf((float)(s0a + s0b), fc0, gv0);                         \
        float p1 = fmaf((float)(s1a + s1b), fc1, gv1);                         \
        float p2 = fmaf((float)(s2a + s2b), fc2, gv2);                         \
        float p3 = fmaf((float)(s3a + s3b), fc3, gv3);                         \
        float a0v = aa / (1.f + __expf(bb * p0)) + cc;                         \
        float a1v = aa / (1.f + __expf(bb * p1)) + cc;                         \
        float a2v = aa / (1.f + __expf(bb * p2)) + cc;                         \
        float a3v = aa / (1.f + __expf(bb * p3)) + cc;                         \
        float i0 = dpp_bcast<0x00>(a0v), f0 = dpp_bcast<0x55>(a0v);            \
        float g0v = dpp_bcast<0xAA>(a0v), o0 = dpp_bcast<0xFF>(a0v);           \
        float i1 = dpp_bcast<0x00>(a1v), f1 = dpp_bcast<0x55>(a1v);            \
        float g1v = dpp_bcast<0xAA>(a1v), o1 = dpp_bcast<0xFF>(a1v);           \
        float i2 = dpp_bcast<0x00>(a2v), f2 = dpp_bcast<0x55>(a2v);            \
        float g2v = dpp_bcast<0xAA>(a2v), o2 = dpp_bcast<0xFF>(a2v);           \
        float i3 = dpp_bcast<0x00>(a3v), f3 = dpp_bcast<0x55>(a3v);            \
        float g3v = dpp_bcast<0xAA>(a3v), o3 = dpp_bcast<0xFF>(a3v);           \
        c0 = f0 * c0 + i0 * g0v;  c1 = f1 * c1 + i1 * g1v;                     \
        c2 = f2 * c2 + i2 * g2v;  c3 = f3 * c3 + i3 * g3v;                     \
        float h0 = o0 * (2.f / (1.f + __expf(-2.f * c0)) - 1.f);               \
        float h1 = o1 * (2.f / (1.f + __expf(-2.f * c1)) - 1.f);               \
        float h2 = o2 * (2.f / (1.f + __expf(-2.f * c2)) - 1.f);               \
        float h3 = o3 * (2.f / (1.f + __expf(-2.f * c3)) - 1.f);               \
        if (q0) {                                                              \
            float* hc = hcomp + (size_t)((T) + 1) * HD;                        \
            hc[u0] = h0; hc[u0 + 64] = h1; hc[u0 + 128] = h2; hc[u0 + 192] = h3;\
            unsigned pk = ((unsigned)((int)rintf(h0 * 127.f) & 0xff)) |        \
                          ((unsigned)((int)rintf(h1 * 127.f) & 0xff) << 8) |   \
                          ((unsigned)((int)rintf(h2 * 127.f) & 0xff) << 16) |  \
                          ((unsigned)((int)rintf(h3 * 127.f) & 0xff) << 24);   \
            hq[((T) + 1) & 1][u0] = pk;                                        \
        }                                                                      \
        __syncthreads();                                                       \
    }

    for (int t = 0; t < SEQ; t += 2) {
        LSTM_STEP(t,     ga0, ga1, ga2, ga3);
        LSTM_STEP(t + 1, gb0, gb1, gb2, gb3);
    }
#undef LSTM_STEP
}

// ---------------------------------------------------------------- feats = [hf,hr] @ w_out^T + b
__global__ __launch_bounds__(256) void feats_kernel(
    const float* __restrict__ hf_buf, const float* __restrict__ hr_buf,
    const float* __restrict__ w_out, const float* __restrict__ b_out,
    float* __restrict__ feats)
{
    __shared__ __align__(16) float wt_lds[256][36];
    int tid = threadIdx.x;
    int t   = blockIdx.x * 256 + tid;

    float acc[32];
#pragma unroll
    for (int g = 0; g < 32; ++g) acc[g] = b_out[g];

    for (int half = 0; half < 2; ++half) {
        __syncthreads();
        for (int tag = 0; tag < 32; ++tag)
            wt_lds[tid][tag] = w_out[tag * 512 + half * 256 + tid];
        __syncthreads();

        const float* hsrc = (half == 0) ? &hf_buf[(size_t)(t + 1) * HD]
                                        : &hr_buf[(size_t)(SEQ - t) * HD];
        for (int k = 0; k < 256; k += 4) {
            float4 hv = *reinterpret_cast<const float4*>(&hsrc[k]);
#pragma unroll
            for (int kk = 0; kk < 4; ++kk) {
                float hx = (kk == 0) ? hv.x : (kk == 1) ? hv.y : (kk == 2) ? hv.z : hv.w;
#pragma unroll
                for (int qq = 0; qq < 8; ++qq) {
                    float4 wv = *reinterpret_cast<const float4*>(&wt_lds[k + kk][4 * qq]);
                    acc[4 * qq + 0] = fmaf(hx, wv.x, acc[4 * qq + 0]);
                    acc[4 * qq + 1] = fmaf(hx, wv.y, acc[4 * qq + 1]);
                    acc[4 * qq + 2] = fmaf(hx, wv.z, acc[4 * qq + 2]);
                    acc[4 * qq + 3] = fmaf(hx, wv.w, acc[4 * qq + 3]);
                }
            }
        }
    }
#pragma unroll
    for (int qq = 0; qq < 8; ++qq) {
        float4 o;
        o.x = acc[4 * qq + 0]; o.y = acc[4 * qq + 1];
        o.z = acc[4 * qq + 2]; o.w = acc[4 * qq + 3];
        *reinterpret_cast<float4*>(&feats[(size_t)t * 32 + 4 * qq]) = o;
    }
}

// ---------------------------------------------------------------- viterbi DP, register-resident
__global__ void viterbi_dp(const float* __restrict__ feats,
                           const float* __restrict__ trans,
                           unsigned char* __restrict__ bp,
                           float* __restrict__ out, int* __restrict__ best_ws)
{
    int l = threadIdx.x;
    int n = l & 31, h = l >> 5;

    float Tn[16];
    int   addr[16], pidx[16];
#pragma unroll
    for (int j = 0; j < 16; ++j) {
        Tn[j]   = trans[n * 32 + 16 * h + j];
        addr[j] = (16 * h + j) * 4;
        pidx[j] = 16 * h + j;
    }

    float vcur = (n == 30) ? 0.0f : NEGV;      // START = 30

    const float* fptr = feats + n;
    float fa = fptr[0], fb = fptr[32], fc = fptr[64], fd = fptr[96];

#define VSTEP(TT, FV)                                                          \
    {                                                                          \
        float cand[16]; int idx[16];                                           \
        _Pragma("unroll")                                                      \
        for (int j = 0; j < 16; ++j) {                                         \
            float pv = __int_as_float(                                         \
                __builtin_amdgcn_ds_bpermute(addr[j], __float_as_int(vcur)));  \
            cand[j] = pv + Tn[j];                                              \
            idx[j] = pidx[j];                                                  \
        }                                                                      \
        _Pragma("unroll")                                                      \
        for (int st = 1; st < 16; st <<= 1)                                    \
            _Pragma("unroll")                                                  \
            for (int p = 0; p < 16; p += 2 * st) {                             \
                bool rgt = cand[p + st] > cand[p];   /* left wins ties */      \
                cand[p] = rgt ? cand[p + st] : cand[p];                        \
                idx[p]  = rgt ? idx[p + st]  : idx[p];                         \
            }                                                                  \
        float ob = __shfl_xor(cand[0], 32);                                    \
        int   oa = __shfl_xor(idx[0], 32);                                     \
        bool useOther = h ? (ob >= cand[0]) : (ob > cand[0]);                  \
        float best = useOther ? ob : cand[0];                                  \
        int   aarg = useOther ? oa : idx[0];                                   \
        if (h == 0) bp[(size_t)(TT) * 32 + n] = (unsigned char)aarg;           \
        vcur = best + (FV);                                                    \
    }

    for (int t = 0; t < SEQ; t += 4) {
        int t4 = (t + 4 < SEQ) ? (t + 4) : (SEQ - 4);
        float na = fptr[(size_t)(t4 + 0) * 32];
        float nb = fptr[(size_t)(t4 + 1) * 32];
        float nc = fptr[(size_t)(t4 + 2) * 32];
        float nd = fptr[(size_t)(t4 + 3) * 32];
        VSTEP(t + 0, fa);
        VSTEP(t + 1, fb);
        VSTEP(t + 2, fc);
        VSTEP(t + 3, fd);
        fa = na; fb = nb; fc = nc; fd = nd;
    }
#undef VSTEP

    float term = vcur + trans[31 * 32 + n];
    int idxv = n;
#pragma unroll
    for (int off = 1; off < 32; off <<= 1) {
        float ot = __shfl_xor(term, off);
        int   oi = __shfl_xor(idxv, off);
        if (ot > term || (ot == term && oi < idxv)) { term = ot; idxv = oi; }
    }
    if (l == 0) { out[0] = term; best_ws[0] = idxv; }
}

// ---------------------------------------------------------------- backtrace, 3 phases (proven)
__global__ void bt_chunks(const unsigned char* __restrict__ bp, unsigned char* __restrict__ G) {
    __shared__ unsigned char lbp[32][32];
    int c = blockIdx.x, tid = threadIdx.x;   // 64 threads
    reinterpret_cast<int4*>(lbp)[tid] = reinterpret_cast<const int4*>(bp + (size_t)c * 1024)[tid];
    __syncthreads();
    if (tid < 32) {
        int cur = tid;
#pragma unroll 8
        for (int i = 31; i >= 0; --i) cur = lbp[i][cur];
        G[c * 32 + tid] = (unsigned char)cur;
    }
}
__global__ void bt_boundaries(const unsigned char* __restrict__ G, const int* __restrict__ best,
                              unsigned char* __restrict__ E) {
    __shared__ unsigned char lG[256 * 32];
    int tid = threadIdx.x;                   // 256 threads
    reinterpret_cast<int4*>(lG)[tid]       = reinterpret_cast<const int4*>(G)[tid];
    reinterpret_cast<int4*>(lG)[256 + tid] = reinterpret_cast<const int4*>(G)[256 + tid];
    __syncthreads();
    if (tid == 0) {
        int e = *best;
        E[255] = (unsigned char)e;
        for (int ch = 255; ch >= 1; --ch) { e = lG[ch * 32 + e]; E[ch - 1] = (unsigned char)e; }
    }
}
__global__ void bt_emit(const unsigned char* __restrict__ bp, const unsigned char* __restrict__ E,
                        float* __restrict__ out) {
    __shared__ unsigned char lbp[32][32];
    int c = blockIdx.x, tid = threadIdx.x;   // 64 threads
    reinterpret_cast<int4*>(lbp)[tid] = reinterpret_cast<const int4*>(bp + (size_t)c * 1024)[tid];
    __syncthreads();
    if (tid == 0) {
        int tag = E[c];
        for (int i = 31; i >= 0; --i) {
            out[1 + (size_t)c * 32 + i] = (float)tag;
            tag = lbp[i][tag];
        }
    }
}

// ---------------------------------------------------------------- launch
extern "C" void kernel_launch(void* const* d_in, const int* in_sizes, int n_in,
                              void* d_out, int out_size, void* d_ws, size_t ws_size,
                              hipStream_t stream)
{
    const int*   sentence = (const int*)d_in[0];
    const float* emb      = (const float*)d_in[1];
    const float* w_ih_f   = (const float*)d_in[2];
    const float* w_hh_f   = (const float*)d_in[3];
    const float* b_ih_f   = (const float*)d_in[4];
    const float* b_hh_f   = (const float*)d_in[5];
    const float* w_ih_r   = (const float*)d_in[6];
    const float* w_hh_r   = (const float*)d_in[7];
    const float* b_ih_r   = (const float*)d_in[8];
    const float* b_hh_r   = (const float*)d_in[9];
    const float* w_out    = (const float*)d_in[10];
    const float* b_out    = (const float*)d_in[11];
    const float* trans    = (const float*)d_in[12];
    (void)in_sizes; (void)n_in; (void)out_size; (void)ws_size;

    char* ws = (char*)d_ws;
    size_t off = 0;
    auto alloc = [&](size_t bytes) -> void* {
        void* p = (void*)(ws + off);
        off += (bytes + 255) & ~(size_t)255;
        return p;
    };
    float* gin_f   = (float*)alloc((size_t)SEQ * G4 * 4);          // 32 MiB
    float* gin_r   = (float*)alloc((size_t)SEQ * G4 * 4);          // 32 MiB
    float* hcomp_f = (float*)alloc((size_t)(SEQ + 1) * HD * 4);    // 8 MiB
    float* hcomp_r = (float*)alloc((size_t)(SEQ + 1) * HD * 4);    // 8 MiB
    float* wt_f    = (float*)alloc((size_t)EMBD * G4 * 4);         // 1 MiB
    float* wt_r    = (float*)alloc((size_t)EMBD * G4 * 4);         // 1 MiB
    float* bs_f    = (float*)alloc(G4 * 4);
    float* bs_r    = (float*)alloc(G4 * 4);
    unsigned* wq   = (unsigned*)alloc(2 * 65536 * 4);              // 512 KiB
    float* fac     = (float*)alloc(2 * 1024 * 4);
    float* feats   = (float*)alloc((size_t)SEQ * 32 * 4);          // 1 MiB
    unsigned char* bp = (unsigned char*)alloc((size_t)SEQ * 32);   // 256 KiB
    unsigned char* G  = (unsigned char*)alloc(256 * 32);           // 8 KiB
    unsigned char* E  = (unsigned char*)alloc(256);
    int* best_ws      = (int*)alloc(256);

    bias_kernel<<<1, 256, 0, stream>>>(b_ih_f, b_hh_f, b_ih_r, b_hh_r, bs_f, bs_r);
    wtrans_kernel<<<64, 256, 0, stream>>>(w_ih_f, w_ih_r, wt_f, wt_r);
    wquant_kernel<<<2048, 64, 0, stream>>>(w_hh_f, w_hh_r, wq, fac);
    gin_kernel<<<SEQ / 32, 256, 0, stream>>>(sentence, emb, wt_f, wt_r, bs_f, bs_r,
                                             gin_f, gin_r);
    lstm_kernel<<<2, 256, 0, stream>>>(wq, fac, gin_f, gin_r, hcomp_f, hcomp_r);
    feats_kernel<<<SEQ / 256, 256, 0, stream>>>(hcomp_f, hcomp_r, w_out, b_out, feats);
    viterbi_dp<<<1, 64, 0, stream>>>(feats, trans, bp, (float*)d_out, best_ws);
    bt_chunks<<<256, 64, 0, stream>>>(bp, G);
    bt_boundaries<<<1, 256, 0, stream>>>(G, best_ws, E);
    bt_emit<<<256, 64, 0, stream>>>(bp, E, (float*)d_out);
}

// Round 11
// 11775.163 us; speedup vs baseline: 1.3412x; 1.3412x over previous
//
#include <hip/hip_runtime.h>

// BiLSTM-CRF forward on MI355X.
//   bias:    bias sums.
//   wtrans:  LDS-tiled transpose of W_ih to [k][row].
//   wquant:  per-row int8 quantization of W_hh -> wq[dir][kdword][rp] (natural k,
//            rp = u*4+gate).
//   gin:     embedding gather + input projection -> gin[t][rp].
//   lstm:    2 blocks x 1024 threads (one CU per direction), 16 waves (4/SIMD —
//            empirically the best latency-hiding shape: R6 1850cy < R9 2520 <
//            R10 3860 cy/step). Thread = one gate row (w[64] dwords in regs,
//            no reduction shuffles). Per step: 16 broadcast ds_read_b128
//            streamed in 4-chunk groups (<=16 live h regs), 64 sdot4 in 4
//            indep chains (depth 16), 1 uniform-gate activation, DPP quad
//            gather, all-lane redundant cell update, masked byte h-write,
//            one barrier, distance-2 gin prefetch.
//   feats:   [hf,hr] @ w_out^T + b_out.
//   viterbi: register-resident single-wave DP (proven) + 3-phase backtrace.

#define SEQ  8192
#define EMBD 256
#define HD   256
#define G4   1024
#define NEGV -10000.0f

#if __has_builtin(__builtin_amdgcn_sdot4)
__device__ __forceinline__ int SDOT4(unsigned a, unsigned b, int c) {
    return __builtin_amdgcn_sdot4((int)a, (int)b, c, false);
}
#else
__device__ __forceinline__ int SDOT4(unsigned a, unsigned b, int c) {
#pragma unroll
    for (int i = 0; i < 4; ++i) {
        int ai = (int)(a << (24 - 8 * i)) >> 24;
        int bi = (int)(b << (24 - 8 * i)) >> 24;
        c += ai * bi;
    }
    return c;
}
#endif

// DPP quad_perm broadcast (VALU pipe): every lane gets its quad's position-K value
template <int CTRL>
__device__ __forceinline__ float dpp_bcast(float x) {
    return __int_as_float(
        __builtin_amdgcn_mov_dpp(__float_as_int(x), CTRL, 0xf, 0xf, true));
}

// ---------------------------------------------------------------- bias sums
__global__ void bias_kernel(const float* __restrict__ b_ih_f, const float* __restrict__ b_hh_f,
                            const float* __restrict__ b_ih_r, const float* __restrict__ b_hh_r,
                            float* __restrict__ bs_f, float* __restrict__ bs_r) {
    int i = threadIdx.x;
#pragma unroll
    for (int m = 0; m < 4; ++m) {
        int row = i + 256 * m;
        bs_f[row] = b_ih_f[row] + b_hh_f[row];
        bs_r[row] = b_ih_r[row] + b_hh_r[row];
    }
}

// ---------------------------------------------------------------- W_ih transpose (tiled)
__global__ __launch_bounds__(256) void wtrans_kernel(
    const float* __restrict__ w_ih_f, const float* __restrict__ w_ih_r,
    float* __restrict__ wt_f, float* __restrict__ wt_r) {
    __shared__ float tile[32][257];
    int mat = blockIdx.x & 1;
    int r0  = (blockIdx.x >> 1) << 5;          // 0,32,...,992
    const float* src = mat ? w_ih_r : w_ih_f;
    float*       dst = mat ? wt_r   : wt_f;
    int tid = threadIdx.x;
    for (int r = 0; r < 32; ++r)
        tile[r][tid] = src[(size_t)(r0 + r) * EMBD + tid];
    __syncthreads();
    int row = tid & 31, kq = tid >> 5;
    for (int kb = 0; kb < EMBD; kb += 8) {
        int k = kb + kq;
        dst[(size_t)k * G4 + r0 + row] = tile[row][k];
    }
}

// ---------------------------------------------------------------- W_hh int8 quantization
// 2048 blocks x 64 threads: dir=b>>10, permuted row rp=b&1023 (rp=u*4+gate,
// original row = gate*256+u). Layout wq[dir][kdword l][rp] -> lstm loads coalesced.
__global__ __launch_bounds__(64) void wquant_kernel(
    const float* __restrict__ w_hh_f, const float* __restrict__ w_hh_r,
    unsigned* __restrict__ wq, float* __restrict__ fac)
{
    int b = blockIdx.x;
    int dir = b >> 10, rp = b & 1023;
    int row = (rp & 3) * 256 + (rp >> 2);
    int l = threadIdx.x;                       // kdword 0..63
    const float* W = dir ? w_hh_r : w_hh_f;
    float4 v = reinterpret_cast<const float4*>(W + (size_t)row * HD)[l];
    float m = fmaxf(fmaxf(fabsf(v.x), fabsf(v.y)), fmaxf(fabsf(v.z), fabsf(v.w)));
#pragma unroll
    for (int off = 1; off < 64; off <<= 1) m = fmaxf(m, __shfl_xor(m, off));
    m = fmaxf(m, 1e-20f);
    float inv = 127.f / m;
    int q0 = (int)rintf(v.x * inv), q1 = (int)rintf(v.y * inv);
    int q2 = (int)rintf(v.z * inv), q3 = (int)rintf(v.w * inv);
    unsigned pk = (unsigned)(q0 & 0xff) | ((unsigned)(q1 & 0xff) << 8) |
                  ((unsigned)(q2 & 0xff) << 16) | ((unsigned)(q3 & 0xff) << 24);
    wq[(size_t)dir * 65536 + (size_t)l * 1024 + rp] = pk;
    if (l == 0) fac[dir * 1024 + rp] = m / (127.f * 127.f);   // dequant scale
}

// ---------------------------------------------------------------- input projection
// writes gin[t][rp] with rp = u*4+gate (bias included)
__global__ __launch_bounds__(256) void gin_kernel(
    const int* __restrict__ sentence, const float* __restrict__ emb,
    const float* __restrict__ wt_f, const float* __restrict__ wt_r,
    const float* __restrict__ bs_f, const float* __restrict__ bs_r,
    float* __restrict__ gin_f, float* __restrict__ gin_r)
{
    __shared__ float x_lds[32][EMBD];
    __shared__ int   sid_lds[32];
    int t0  = blockIdx.x * 32;
    int tid = threadIdx.x;
    if (tid < 32) sid_lds[tid] = sentence[t0 + tid];
    __syncthreads();
    for (int i = 0; i < 32; ++i)
        x_lds[i][tid] = emb[(size_t)sid_lds[i] * EMBD + tid];
    __syncthreads();

    float bsv[8];
#pragma unroll
    for (int m = 0; m < 4; ++m) bsv[m]     = bs_f[tid + 256 * m];
#pragma unroll
    for (int m = 0; m < 4; ++m) bsv[4 + m] = bs_r[tid + 256 * m];

    for (int tsub = 0; tsub < 4; ++tsub) {
        float acc[8][8];
#pragma unroll
        for (int m = 0; m < 8; ++m)
#pragma unroll
            for (int j = 0; j < 8; ++j) acc[m][j] = bsv[m];

        for (int k = 0; k < EMBD; ++k) {
            float xv[8];
#pragma unroll
            for (int j = 0; j < 8; ++j) xv[j] = x_lds[tsub * 8 + j][k];
#pragma unroll
            for (int m = 0; m < 8; ++m) {
                float wv = (m < 4) ? wt_f[(size_t)k * G4 + tid + 256 * m]
                                   : wt_r[(size_t)k * G4 + tid + 256 * (m - 4)];
#pragma unroll
                for (int j = 0; j < 8; ++j) acc[m][j] = fmaf(wv, xv[j], acc[m][j]);
            }
        }
#pragma unroll
        for (int m = 0; m < 8; ++m) {
            int rp = tid * 4 + (m & 3);        // u = tid, gate = m&3
#pragma unroll
            for (int j = 0; j < 8; ++j) {
                int t = t0 + tsub * 8 + j;
                if (m < 4) gin_f[(size_t)t * G4 + rp] = acc[m][j];
                else       gin_r[(size_t)(SEQ - 1 - t) * G4 + rp] = acc[m][j];
            }
        }
    }
}

// ---------------------------------------------------------------- single-CU LSTM per direction
// 2 blocks x 1024 threads (16 waves, 4/SIMD). Thread tid = gate row rp (unit
// u=tid>>2, gate g=tid&3). w[64] in regs; h streamed from LDS in 4-chunk groups.
__global__ __launch_bounds__(1024, 4) void lstm_kernel(
    const unsigned* __restrict__ wq, const float* __restrict__ fac,
    const float* __restrict__ gin_f, const float* __restrict__ gin_r,
    float* __restrict__ hcomp_f, float* __restrict__ hcomp_r)
{
    int dir = blockIdx.x;
    const float* gin   = dir ? gin_r   : gin_f;
    float*       hcomp = dir ? hcomp_r : hcomp_f;
    int tid = threadIdx.x;
    int g   = tid & 3;
    int u   = tid >> 2;                        // 0..255
    bool q0 = (g == 0);

    unsigned w[64];
    {
        const unsigned* base = wq + (size_t)dir * 65536;
#pragma unroll
        for (int j = 0; j < 64; ++j) w[j] = base[(size_t)j * 1024 + tid];
    }
    float fcr = fac[dir * 1024 + tid];

    __shared__ unsigned hq[2][64];             // int8-packed h, double-buffered
    if (tid < 128) ((unsigned*)hq)[tid] = 0u;  // h(0) = 0 (both buffers)

    // uniform per-gate activation: sigmoid (a=1,b=-1,c=0); tanh=2*sigm(2x)-1
    float aa = (g == 2) ? 2.f : 1.f;
    float bb = (g == 2) ? -2.f : -1.f;
    float cc = (g == 2) ? -1.f : 0.f;
    float c = 0.f;

    float g0 = gin[tid];
    float g1 = gin[G4 + tid];
    __syncthreads();

    for (int t = 0; t < SEQ; ++t) {
        size_t pf = (size_t)((t + 2 < SEQ) ? t + 2 : SEQ - 1) * G4;
        float g2 = gin[pf + tid];              // distance-2 prefetch

        const uint4* hb = reinterpret_cast<const uint4*>(hq[t & 1]);
        int a0 = 0, a1 = 0, a2 = 0, a3 = 0;    // 4 indep chains, depth 16
#pragma unroll
        for (int jj = 0; jj < 4; ++jj) {       // 4-chunk groups: <=16 live h regs
            uint4 h4[4];
#pragma unroll
            for (int k = 0; k < 4; ++k) h4[k] = hb[4 * jj + k];
#pragma unroll
            for (int k = 0; k < 4; ++k) {
                a0 = SDOT4(w[16 * jj + 4 * k + 0], h4[k].x, a0);
                a1 = SDOT4(w[16 * jj + 4 * k + 1], h4[k].y, a1);
                a2 = SDOT4(w[16 * jj + 4 * k + 2], h4[k].z, a2);
                a3 = SDOT4(w[16 * jj + 4 * k + 3], h4[k].w, a3);
            }
        }
        float p = fmaf((float)((a0 + a1) + (a2 + a3)), fcr, g0);
        float act = aa / (1.f + __expf(bb * p)) + cc;      // this row's gate act

        float ig = dpp_bcast<0x00>(act);       // quad lanes: i,f,g,o
        float fg = dpp_bcast<0x55>(act);
        float gg = dpp_bcast<0xAA>(act);
        float og = dpp_bcast<0xFF>(act);

        c = fg * c + ig * gg;                  // all lanes, divergence-free
        float h = og * (2.f / (1.f + __expf(-2.f * c)) - 1.f);

        if (q0) {                              // one lane per unit publishes
            hcomp[(size_t)(t + 1) * HD + u] = h;
            ((char*)hq[(t + 1) & 1])[u] = (char)(int)rintf(h * 127.f);
        }
        __syncthreads();                       // h(t+1) visible; reads of h(t) done
        g0 = g1; g1 = g2;
    }
}

// ---------------------------------------------------------------- feats = [hf,hr] @ w_out^T + b
__global__ __launch_bounds__(256) void feats_kernel(
    const float* __restrict__ hf_buf, const float* __restrict__ hr_buf,
    const float* __restrict__ w_out, const float* __restrict__ b_out,
    float* __restrict__ feats)
{
    __shared__ __align__(16) float wt_lds[256][36];
    int tid = threadIdx.x;
    int t   = blockIdx.x * 256 + tid;

    float acc[32];
#pragma unroll
    for (int g = 0; g < 32; ++g) acc[g] = b_out[g];

    for (int half = 0; half < 2; ++half) {
        __syncthreads();
        for (int tag = 0; tag < 32; ++tag)
            wt_lds[tid][tag] = w_out[tag * 512 + half * 256 + tid];
        __syncthreads();

        const float* hsrc = (half == 0) ? &hf_buf[(size_t)(t + 1) * HD]
                                        : &hr_buf[(size_t)(SEQ - t) * HD];
        for (int k = 0; k < 256; k += 4) {
            float4 hv = *reinterpret_cast<const float4*>(&hsrc[k]);
#pragma unroll
            for (int kk = 0; kk < 4; ++kk) {
                float hx = (kk == 0) ? hv.x : (kk == 1) ? hv.y : (kk == 2) ? hv.z : hv.w;
#pragma unroll
                for (int qq = 0; qq < 8; ++qq) {
                    float4 wv = *reinterpret_cast<const float4*>(&wt_lds[k + kk][4 * qq]);
                    acc[4 * qq + 0] = fmaf(hx, wv.x, acc[4 * qq + 0]);
                    acc[4 * qq + 1] = fmaf(hx, wv.y, acc[4 * qq + 1]);
                    acc[4 * qq + 2] = fmaf(hx, wv.z, acc[4 * qq + 2]);
                    acc[4 * qq + 3] = fmaf(hx, wv.w, acc[4 * qq + 3]);
                }
            }
        }
    }
#pragma unroll
    for (int qq = 0; qq < 8; ++qq) {
        float4 o;
        o.x = acc[4 * qq + 0]; o.y = acc[4 * qq + 1];
        o.z = acc[4 * qq + 2]; o.w = acc[4 * qq + 3];
        *reinterpret_cast<float4*>(&feats[(size_t)t * 32 + 4 * qq]) = o;
    }
}

// ---------------------------------------------------------------- viterbi DP, register-resident
__global__ void viterbi_dp(const float* __restrict__ feats,
                           const float* __restrict__ trans,
                           unsigned char* __restrict__ bp,
                           float* __restrict__ out, int* __restrict__ best_ws)
{
    int l = threadIdx.x;
    int n = l & 31, h = l >> 5;

    float Tn[16];
    int   addr[16], pidx[16];
#pragma unroll
    for (int j = 0; j < 16; ++j) {
        Tn[j]   = trans[n * 32 + 16 * h + j];
        addr[j] = (16 * h + j) * 4;
        pidx[j] = 16 * h + j;
    }

    float vcur = (n == 30) ? 0.0f : NEGV;      // START = 30

    const float* fptr = feats + n;
    float fa = fptr[0], fb = fptr[32], fc = fptr[64], fd = fptr[96];

#define VSTEP(TT, FV)                                                          \
    {                                                                          \
        float cand[16]; int idx[16];                                           \
        _Pragma("unroll")                                                      \
        for (int j = 0; j < 16; ++j) {                                         \
            float pv = __int_as_float(                                         \
                __builtin_amdgcn_ds_bpermute(addr[j], __float_as_int(vcur)));  \
            cand[j] = pv + Tn[j];                                              \
            idx[j] = pidx[j];                                                  \
        }                                                                      \
        _Pragma("unroll")                                                      \
        for (int st = 1; st < 16; st <<= 1)                                    \
            _Pragma("unroll")                                                  \
            for (int p = 0; p < 16; p += 2 * st) {                             \
                bool rgt = cand[p + st] > cand[p];   /* left wins ties */      \
                cand[p] = rgt ? cand[p + st] : cand[p];                        \
                idx[p]  = rgt ? idx[p + st]  : idx[p];                         \
            }                                                                  \
        float ob = __shfl_xor(cand[0], 32);                                    \
        int   oa = __shfl_xor(idx[0], 32);                                     \
        bool useOther = h ? (ob >= cand[0]) : (ob > cand[0]);                  \
        float best = useOther ? ob : cand[0];                                  \
        int   aarg = useOther ? oa : idx[0];                                   \
        if (h == 0) bp[(size_t)(TT) * 32 + n] = (unsigned char)aarg;           \
        vcur = best + (FV);                                                    \
    }

    for (int t = 0; t < SEQ; t += 4) {
        int t4 = (t + 4 < SEQ) ? (t + 4) : (SEQ - 4);
        float na = fptr[(size_t)(t4 + 0) * 32];
        float nb = fptr[(size_t)(t4 + 1) * 32];
        float nc = fptr[(size_t)(t4 + 2) * 32];
        float nd = fptr[(size_t)(t4 + 3) * 32];
        VSTEP(t + 0, fa);
        VSTEP(t + 1, fb);
        VSTEP(t + 2, fc);
        VSTEP(t + 3, fd);
        fa = na; fb = nb; fc = nc; fd = nd;
    }
#undef VSTEP

    float term = vcur + trans[31 * 32 + n];
    int idxv = n;
#pragma unroll
    for (int off = 1; off < 32; off <<= 1) {
        float ot = __shfl_xor(term, off);
        int   oi = __shfl_xor(idxv, off);
        if (ot > term || (ot == term && oi < idxv)) { term = ot; idxv = oi; }
    }
    if (l == 0) { out[0] = term; best_ws[0] = idxv; }
}

// ---------------------------------------------------------------- backtrace, 3 phases (proven)
__global__ void bt_chunks(const unsigned char* __restrict__ bp, unsigned char* __restrict__ G) {
    __shared__ unsigned char lbp[32][32];
    int c = blockIdx.x, tid = threadIdx.x;   // 64 threads
    reinterpret_cast<int4*>(lbp)[tid] = reinterpret_cast<const int4*>(bp + (size_t)c * 1024)[tid];
    __syncthreads();
    if (tid < 32) {
        int cur = tid;
#pragma unroll 8
        for (int i = 31; i >= 0; --i) cur = lbp[i][cur];
        G[c * 32 + tid] = (unsigned char)cur;
    }
}
__global__ void bt_boundaries(const unsigned char* __restrict__ G, const int* __restrict__ best,
                              unsigned char* __restrict__ E) {
    __shared__ unsigned char lG[256 * 32];
    int tid = threadIdx.x;                   // 256 threads
    reinterpret_cast<int4*>(lG)[tid]       = reinterpret_cast<const int4*>(G)[tid];
    reinterpret_cast<int4*>(lG)[256 + tid] = reinterpret_cast<const int4*>(G)[256 + tid];
    __syncthreads();
    if (tid == 0) {
        int e = *best;
        E[255] = (unsigned char)e;
        for (int ch = 255; ch >= 1; --ch) { e = lG[ch * 32 + e]; E[ch - 1] = (unsigned char)e; }
    }
}
__global__ void bt_emit(const unsigned char* __restrict__ bp, const unsigned char* __restrict__ E,
                        float* __restrict__ out) {
    __shared__ unsigned char lbp[32][32];
    int c = blockIdx.x, tid = threadIdx.x;   // 64 threads
    reinterpret_cast<int4*>(lbp)[tid] = reinterpret_cast<const int4*>(bp + (size_t)c * 1024)[tid];
    __syncthreads();
    if (tid == 0) {
        int tag = E[c];
        for (int i = 31; i >= 0; --i) {
            out[1 + (size_t)c * 32 + i] = (float)tag;
            tag = lbp[i][tag];
        }
    }
}

// ---------------------------------------------------------------- launch
extern "C" void kernel_launch(void* const* d_in, const int* in_sizes, int n_in,
                              void* d_out, int out_size, void* d_ws, size_t ws_size,
                              hipStream_t stream)
{
    const int*   sentence = (const int*)d_in[0];
    const float* emb      = (const float*)d_in[1];
    const float* w_ih_f   = (const float*)d_in[2];
    const float* w_hh_f   = (const float*)d_in[3];
    const float* b_ih_f   = (const float*)d_in[4];
    const float* b_hh_f   = (const float*)d_in[5];
    const float* w_ih_r   = (const float*)d_in[6];
    const float* w_hh_r   = (const float*)d_in[7];
    const float* b_ih_r   = (const float*)d_in[8];
    const float* b_hh_r   = (const float*)d_in[9];
    const float* w_out    = (const float*)d_in[10];
    const float* b_out    = (const float*)d_in[11];
    const float* trans    = (const float*)d_in[12];
    (void)in_sizes; (void)n_in; (void)out_size; (void)ws_size;

    char* ws = (char*)d_ws;
    size_t off = 0;
    auto alloc = [&](size_t bytes) -> void* {
        void* p = (void*)(ws + off);
        off += (bytes + 255) & ~(size_t)255;
        return p;
    };
    float* gin_f   = (float*)alloc((size_t)SEQ * G4 * 4);          // 32 MiB
    float* gin_r   = (float*)alloc((size_t)SEQ * G4 * 4);          // 32 MiB
    float* hcomp_f = (float*)alloc((size_t)(SEQ + 1) * HD * 4);    // 8 MiB
    float* hcomp_r = (float*)alloc((size_t)(SEQ + 1) * HD * 4);    // 8 MiB
    float* wt_f    = (float*)alloc((size_t)EMBD * G4 * 4);         // 1 MiB
    float* wt_r    = (float*)alloc((size_t)EMBD * G4 * 4);         // 1 MiB
    float* bs_f    = (float*)alloc(G4 * 4);
    float* bs_r    = (float*)alloc(G4 * 4);
    unsigned* wq   = (unsigned*)alloc(2 * 65536 * 4);              // 512 KiB
    float* fac     = (float*)alloc(2 * 1024 * 4);
    float* feats   = (float*)alloc((size_t)SEQ * 32 * 4);          // 1 MiB
    unsigned char* bp = (unsigned char*)alloc((size_t)SEQ * 32);   // 256 KiB
    unsigned char* G  = (unsigned char*)alloc(256 * 32);           // 8 KiB
    unsigned char* E  = (unsigned char*)alloc(256);
    int* best_ws      = (int*)alloc(256);

    bias_kernel<<<1, 256, 0, stream>>>(b_ih_f, b_hh_f, b_ih_r, b_hh_r, bs_f, bs_r);
    wtrans_kernel<<<64, 256, 0, stream>>>(w_ih_f, w_ih_r, wt_f, wt_r);
    wquant_kernel<<<2048, 64, 0, stream>>>(w_hh_f, w_hh_r, wq, fac);
    gin_kernel<<<SEQ / 32, 256, 0, stream>>>(sentence, emb, wt_f, wt_r, bs_f, bs_r,
                                             gin_f, gin_r);
    lstm_kernel<<<2, 1024, 0, stream>>>(wq, fac, gin_f, gin_r, hcomp_f, hcomp_r);
    feats_kernel<<<SEQ / 256, 256, 0, stream>>>(hcomp_f, hcomp_r, w_out, b_out, feats);
    viterbi_dp<<<1, 64, 0, stream>>>(feats, trans, bp, (float*)d_out, best_ws);
    bt_chunks<<<256, 64, 0, stream>>>(bp, G);
    bt_boundaries<<<1, 256, 0, stream>>>(G, best_ws, E);
    bt_emit<<<256, 64, 0, stream>>>(bp, E, (float*)d_out);
}

// Round 12
// 11655.144 us; speedup vs baseline: 1.3550x; 1.0103x over previous
//
#include <hip/hip_runtime.h>

// BiLSTM-CRF forward on MI355X.
//   bias:    bias sums.
//   wtrans:  LDS-tiled transpose of W_ih to [k][row].
//   wquant:  per-row int8 quantization of W_hh -> QUAD-QUARTER layout:
//            wq[dir][r*16+j][u*4+g] packs W[row(r,u)][g*64+4j .. +3].
//            Lane g of quad u holds the quad's 4 rows over k-quarter g.
//   gin:     embedding gather + input projection -> gin[t][rp] (rp=u*4+gate).
//   lstm:    2 blocks x 1024 threads (16 waves, 4/SIMD — best shape from the
//            R6/R9/R10 occupancy sweep). Per step per lane: 4 ds_read_b128
//            (OWN k-quarter, 4-address 2-way-free pattern) -> 16 h dwords,
//            64 sdot4 partials for the quad's 4 rows, exact int quad
//            all-reduce (2 DPP adds x 4), row select, dequant+act (1 exp),
//            3-DPP gate gather, divergent g==0 cell update, byte h-write,
//            one barrier. DS reads/step: 64 wave-insts (was 256 broadcast).
//   feats:   [hf,hr] @ w_out^T + b_out.
//   viterbi: register-resident single-wave DP (proven) + 3-phase backtrace.

#define SEQ  8192
#define EMBD 256
#define HD   256
#define G4   1024
#define NEGV -10000.0f

#if __has_builtin(__builtin_amdgcn_sdot4)
__device__ __forceinline__ int SDOT4(unsigned a, unsigned b, int c) {
    return __builtin_amdgcn_sdot4((int)a, (int)b, c, false);
}
#else
__device__ __forceinline__ int SDOT4(unsigned a, unsigned b, int c) {
#pragma unroll
    for (int i = 0; i < 4; ++i) {
        int ai = (int)(a << (24 - 8 * i)) >> 24;
        int bi = (int)(b << (24 - 8 * i)) >> 24;
        c += ai * bi;
    }
    return c;
}
#endif

// DPP quad_perm (VALU pipe)
template <int CTRL>
__device__ __forceinline__ float dpp_bcast(float x) {
    return __int_as_float(
        __builtin_amdgcn_mov_dpp(__float_as_int(x), CTRL, 0xf, 0xf, true));
}
template <int CTRL>
__device__ __forceinline__ int idpp(int x) {
    return __builtin_amdgcn_mov_dpp(x, CTRL, 0xf, 0xf, true);
}

// ---------------------------------------------------------------- bias sums
__global__ void bias_kernel(const float* __restrict__ b_ih_f, const float* __restrict__ b_hh_f,
                            const float* __restrict__ b_ih_r, const float* __restrict__ b_hh_r,
                            float* __restrict__ bs_f, float* __restrict__ bs_r) {
    int i = threadIdx.x;
#pragma unroll
    for (int m = 0; m < 4; ++m) {
        int row = i + 256 * m;
        bs_f[row] = b_ih_f[row] + b_hh_f[row];
        bs_r[row] = b_ih_r[row] + b_hh_r[row];
    }
}

// ---------------------------------------------------------------- W_ih transpose (tiled)
__global__ __launch_bounds__(256) void wtrans_kernel(
    const float* __restrict__ w_ih_f, const float* __restrict__ w_ih_r,
    float* __restrict__ wt_f, float* __restrict__ wt_r) {
    __shared__ float tile[32][257];
    int mat = blockIdx.x & 1;
    int r0  = (blockIdx.x >> 1) << 5;          // 0,32,...,992
    const float* src = mat ? w_ih_r : w_ih_f;
    float*       dst = mat ? wt_r   : wt_f;
    int tid = threadIdx.x;
    for (int r = 0; r < 32; ++r)
        tile[r][tid] = src[(size_t)(r0 + r) * EMBD + tid];
    __syncthreads();
    int row = tid & 31, kq = tid >> 5;
    for (int kb = 0; kb < EMBD; kb += 8) {
        int k = kb + kq;
        dst[(size_t)k * G4 + r0 + row] = tile[row][k];
    }
}

// ---------------------------------------------------------------- W_hh int8 quantization
// 2048 blocks x 64 threads: dir=b>>10, rp=b&1023 (rp=u*4+r, original row
// = r*256+u). Thread l: j=l&15, g=l>>4. QUAD-QUARTER layout:
// wq[dir][(r*16+j)*1024 + u*4+g] = pack(W[row][g*64+4j .. +3]).
__global__ __launch_bounds__(64) void wquant_kernel(
    const float* __restrict__ w_hh_f, const float* __restrict__ w_hh_r,
    unsigned* __restrict__ wq, float* __restrict__ fac)
{
    int b = blockIdx.x;
    int dir = b >> 10, rp = b & 1023;
    int u = rp >> 2, r = rp & 3;
    int row = r * 256 + u;
    int l = threadIdx.x;
    int j = l & 15, g = l >> 4;
    const float* Wr = (dir ? w_hh_r : w_hh_f) + (size_t)row * HD;
    float4 v = reinterpret_cast<const float4*>(Wr)[g * 16 + j];   // k = g*64+4j
    float m = fmaxf(fmaxf(fabsf(v.x), fabsf(v.y)), fmaxf(fabsf(v.z), fabsf(v.w)));
#pragma unroll
    for (int off = 1; off < 64; off <<= 1) m = fmaxf(m, __shfl_xor(m, off));
    m = fmaxf(m, 1e-20f);
    float inv = 127.f / m;
    int q0 = (int)rintf(v.x * inv), q1 = (int)rintf(v.y * inv);
    int q2 = (int)rintf(v.z * inv), q3 = (int)rintf(v.w * inv);
    unsigned pk = (unsigned)(q0 & 0xff) | ((unsigned)(q1 & 0xff) << 8) |
                  ((unsigned)(q2 & 0xff) << 16) | ((unsigned)(q3 & 0xff) << 24);
    wq[(size_t)dir * 65536 + (size_t)(r * 16 + j) * 1024 + u * 4 + g] = pk;
    if (l == 0) fac[dir * 1024 + rp] = m / (127.f * 127.f);   // dequant scale
}

// ---------------------------------------------------------------- input projection
// writes gin[t][rp] with rp = u*4+gate (bias included)
__global__ __launch_bounds__(256) void gin_kernel(
    const int* __restrict__ sentence, const float* __restrict__ emb,
    const float* __restrict__ wt_f, const float* __restrict__ wt_r,
    const float* __restrict__ bs_f, const float* __restrict__ bs_r,
    float* __restrict__ gin_f, float* __restrict__ gin_r)
{
    __shared__ float x_lds[32][EMBD];
    __shared__ int   sid_lds[32];
    int t0  = blockIdx.x * 32;
    int tid = threadIdx.x;
    if (tid < 32) sid_lds[tid] = sentence[t0 + tid];
    __syncthreads();
    for (int i = 0; i < 32; ++i)
        x_lds[i][tid] = emb[(size_t)sid_lds[i] * EMBD + tid];
    __syncthreads();

    float bsv[8];
#pragma unroll
    for (int m = 0; m < 4; ++m) bsv[m]     = bs_f[tid + 256 * m];
#pragma unroll
    for (int m = 0; m < 4; ++m) bsv[4 + m] = bs_r[tid + 256 * m];

    for (int tsub = 0; tsub < 4; ++tsub) {
        float acc[8][8];
#pragma unroll
        for (int m = 0; m < 8; ++m)
#pragma unroll
            for (int j = 0; j < 8; ++j) acc[m][j] = bsv[m];

        for (int k = 0; k < EMBD; ++k) {
            float xv[8];
#pragma unroll
            for (int j = 0; j < 8; ++j) xv[j] = x_lds[tsub * 8 + j][k];
#pragma unroll
            for (int m = 0; m < 8; ++m) {
                float wv = (m < 4) ? wt_f[(size_t)k * G4 + tid + 256 * m]
                                   : wt_r[(size_t)k * G4 + tid + 256 * (m - 4)];
#pragma unroll
                for (int j = 0; j < 8; ++j) acc[m][j] = fmaf(wv, xv[j], acc[m][j]);
            }
        }
#pragma unroll
        for (int m = 0; m < 8; ++m) {
            int rp = tid * 4 + (m & 3);        // u = tid, gate = m&3
#pragma unroll
            for (int j = 0; j < 8; ++j) {
                int t = t0 + tsub * 8 + j;
                if (m < 4) gin_f[(size_t)t * G4 + rp] = acc[m][j];
                else       gin_r[(size_t)(SEQ - 1 - t) * G4 + rp] = acc[m][j];
            }
        }
    }
}

// ---------------------------------------------------------------- single-CU LSTM per direction
// 2 blocks x 1024 threads (16 waves, 4/SIMD). Thread tid=(u=tid>>2, g=tid&3):
// holds quad u's 4 rows over k-quarter g (w[64]); reads its quarter of h.
__global__ __launch_bounds__(1024, 4) void lstm_kernel(
    const unsigned* __restrict__ wq, const float* __restrict__ fac,
    const float* __restrict__ gin_f, const float* __restrict__ gin_r,
    float* __restrict__ hcomp_f, float* __restrict__ hcomp_r)
{
    int dir = blockIdx.x;
    const float* gin   = dir ? gin_r   : gin_f;
    float*       hcomp = dir ? hcomp_r : hcomp_f;
    int tid = threadIdx.x;
    int g   = tid & 3;
    int u   = tid >> 2;                        // 0..255
    bool q0 = (g == 0);

    unsigned w[64];                            // w[r*16+j]: row r, quarter-dword j
    {
        const unsigned* base = wq + (size_t)dir * 65536;
#pragma unroll
        for (int j = 0; j < 64; ++j) w[j] = base[(size_t)j * 1024 + tid];
    }
    float4 fac4 = *reinterpret_cast<const float4*>(&fac[dir * 1024 + (u << 2)]);

    __shared__ unsigned hq[2][64];             // int8-packed h, double-buffered
    if (tid < 128) ((unsigned*)hq)[tid] = 0u;  // h(0) = 0 (both buffers)

    // uniform per-gate activation: sigmoid (a=1,b=-1,c=0); tanh=2*sigm(2x)-1
    float aa = (g == 2) ? 2.f : 1.f;
    float bb = (g == 2) ? -2.f : -1.f;
    float cc = (g == 2) ? -1.f : 0.f;
    float c = 0.f;

    float g0 = gin[tid];
    float g1 = gin[G4 + tid];
    __syncthreads();

    for (int t = 0; t < SEQ; ++t) {
        size_t pf = (size_t)((t + 2 < SEQ) ? t + 2 : SEQ - 1) * G4;
        float g2 = gin[pf + tid];              // distance-2 prefetch

        // own k-quarter of h: 4 x ds_read_b128 at byte g*64+16i
        // (4-address pattern, 2-way bank alias = free)
        const uint4* hb =
            reinterpret_cast<const uint4*>((const char*)hq[t & 1] + g * 64);
        uint4 h4[4];
#pragma unroll
        for (int i = 0; i < 4; ++i) h4[i] = hb[i];

        int s0 = 0, s1 = 0, s2 = 0, s3 = 0;    // partials for quad rows 0..3
#pragma unroll
        for (int i = 0; i < 4; ++i) {
            s0 = SDOT4(w[0 * 16 + 4 * i + 0], h4[i].x, s0);
            s1 = SDOT4(w[1 * 16 + 4 * i + 0], h4[i].x, s1);
            s2 = SDOT4(w[2 * 16 + 4 * i + 0], h4[i].x, s2);
            s3 = SDOT4(w[3 * 16 + 4 * i + 0], h4[i].x, s3);
            s0 = SDOT4(w[0 * 16 + 4 * i + 1], h4[i].y, s0);
            s1 = SDOT4(w[1 * 16 + 4 * i + 1], h4[i].y, s1);
            s2 = SDOT4(w[2 * 16 + 4 * i + 1], h4[i].y, s2);
            s3 = SDOT4(w[3 * 16 + 4 * i + 1], h4[i].y, s3);
            s0 = SDOT4(w[0 * 16 + 4 * i + 2], h4[i].z, s0);
            s1 = SDOT4(w[1 * 16 + 4 * i + 2], h4[i].z, s1);
            s2 = SDOT4(w[2 * 16 + 4 * i + 2], h4[i].z, s2);
            s3 = SDOT4(w[3 * 16 + 4 * i + 2], h4[i].z, s3);
            s0 = SDOT4(w[0 * 16 + 4 * i + 3], h4[i].w, s0);
            s1 = SDOT4(w[1 * 16 + 4 * i + 3], h4[i].w, s1);
            s2 = SDOT4(w[2 * 16 + 4 * i + 3], h4[i].w, s2);
            s3 = SDOT4(w[3 * 16 + 4 * i + 3], h4[i].w, s3);
        }
        // exact int quad all-reduce (VALU DPP): every lane gets all 4 row sums
        int r0 = s0 + idpp<0xB1>(s0); r0 += idpp<0x4E>(r0);
        int r1 = s1 + idpp<0xB1>(s1); r1 += idpp<0x4E>(r1);
        int r2 = s2 + idpp<0xB1>(s2); r2 += idpp<0x4E>(r2);
        int r3 = s3 + idpp<0xB1>(s3); r3 += idpp<0x4E>(r3);

        int   ps = (g == 0) ? r0 : (g == 1) ? r1 : (g == 2) ? r2 : r3;
        float fs = (g == 0) ? fac4.x : (g == 1) ? fac4.y : (g == 2) ? fac4.z : fac4.w;

        float p   = fmaf((float)ps, fs, g0);
        float act = aa / (1.f + __expf(bb * p)) + cc;      // this row's gate act

        float xf = dpp_bcast<0x55>(act);       // f-gate (quad lane 1)
        float xg = dpp_bcast<0xAA>(act);       // g-gate (quad lane 2)
        float xo = dpp_bcast<0xFF>(act);       // o-gate (quad lane 3)

        if (q0) {                              // act = i; one lane per unit
            c = xf * c + act * xg;
            float h = xo * (2.f / (1.f + __expf(-2.f * c)) - 1.f);
            hcomp[(size_t)(t + 1) * HD + u] = h;
            ((char*)hq[(t + 1) & 1])[u] = (char)(int)rintf(h * 127.f);
        }
        __syncthreads();                       // h(t+1) visible; reads of h(t) done
        g0 = g1; g1 = g2;
    }
}

// ---------------------------------------------------------------- feats = [hf,hr] @ w_out^T + b
__global__ __launch_bounds__(256) void feats_kernel(
    const float* __restrict__ hf_buf, const float* __restrict__ hr_buf,
    const float* __restrict__ w_out, const float* __restrict__ b_out,
    float* __restrict__ feats)
{
    __shared__ __align__(16) float wt_lds[256][36];
    int tid = threadIdx.x;
    int t   = blockIdx.x * 256 + tid;

    float acc[32];
#pragma unroll
    for (int g = 0; g < 32; ++g) acc[g] = b_out[g];

    for (int half = 0; half < 2; ++half) {
        __syncthreads();
        for (int tag = 0; tag < 32; ++tag)
            wt_lds[tid][tag] = w_out[tag * 512 + half * 256 + tid];
        __syncthreads();

        const float* hsrc = (half == 0) ? &hf_buf[(size_t)(t + 1) * HD]
                                        : &hr_buf[(size_t)(SEQ - t) * HD];
        for (int k = 0; k < 256; k += 4) {
            float4 hv = *reinterpret_cast<const float4*>(&hsrc[k]);
#pragma unroll
            for (int kk = 0; kk < 4; ++kk) {
                float hx = (kk == 0) ? hv.x : (kk == 1) ? hv.y : (kk == 2) ? hv.z : hv.w;
#pragma unroll
                for (int qq = 0; qq < 8; ++qq) {
                    float4 wv = *reinterpret_cast<const float4*>(&wt_lds[k + kk][4 * qq]);
                    acc[4 * qq + 0] = fmaf(hx, wv.x, acc[4 * qq + 0]);
                    acc[4 * qq + 1] = fmaf(hx, wv.y, acc[4 * qq + 1]);
                    acc[4 * qq + 2] = fmaf(hx, wv.z, acc[4 * qq + 2]);
                    acc[4 * qq + 3] = fmaf(hx, wv.w, acc[4 * qq + 3]);
                }
            }
        }
    }
#pragma unroll
    for (int qq = 0; qq < 8; ++qq) {
        float4 o;
        o.x = acc[4 * qq + 0]; o.y = acc[4 * qq + 1];
        o.z = acc[4 * qq + 2]; o.w = acc[4 * qq + 3];
        *reinterpret_cast<float4*>(&feats[(size_t)t * 32 + 4 * qq]) = o;
    }
}

// ---------------------------------------------------------------- viterbi DP, register-resident
__global__ void viterbi_dp(const float* __restrict__ feats,
                           const float* __restrict__ trans,
                           unsigned char* __restrict__ bp,
                           float* __restrict__ out, int* __restrict__ best_ws)
{
    int l = threadIdx.x;
    int n = l & 31, h = l >> 5;

    float Tn[16];
    int   addr[16], pidx[16];
#pragma unroll
    for (int j = 0; j < 16; ++j) {
        Tn[j]   = trans[n * 32 + 16 * h + j];
        addr[j] = (16 * h + j) * 4;
        pidx[j] = 16 * h + j;
    }

    float vcur = (n == 30) ? 0.0f : NEGV;      // START = 30

    const float* fptr = feats + n;
    float fa = fptr[0], fb = fptr[32], fc = fptr[64], fd = fptr[96];

#define VSTEP(TT, FV)                                                          \
    {                                                                          \
        float cand[16]; int idx[16];                                           \
        _Pragma("unroll")                                                      \
        for (int j = 0; j < 16; ++j) {                                         \
            float pv = __int_as_float(                                         \
                __builtin_amdgcn_ds_bpermute(addr[j], __float_as_int(vcur)));  \
            cand[j] = pv + Tn[j];                                              \
            idx[j] = pidx[j];                                                  \
        }                                                                      \
        _Pragma("unroll")                                                      \
        for (int st = 1; st < 16; st <<= 1)                                    \
            _Pragma("unroll")                                                  \
            for (int p = 0; p < 16; p += 2 * st) {                             \
                bool rgt = cand[p + st] > cand[p];   /* left wins ties */      \
                cand[p] = rgt ? cand[p + st] : cand[p];                        \
                idx[p]  = rgt ? idx[p + st]  : idx[p];                         \
            }                                                                  \
        float ob = __shfl_xor(cand[0], 32);                                    \
        int   oa = __shfl_xor(idx[0], 32);                                     \
        bool useOther = h ? (ob >= cand[0]) : (ob > cand[0]);                  \
        float best = useOther ? ob : cand[0];                                  \
        int   aarg = useOther ? oa : idx[0];                                   \
        if (h == 0) bp[(size_t)(TT) * 32 + n] = (unsigned char)aarg;           \
        vcur = best + (FV);                                                    \
    }

    for (int t = 0; t < SEQ; t += 4) {
        int t4 = (t + 4 < SEQ) ? (t + 4) : (SEQ - 4);
        float na = fptr[(size_t)(t4 + 0) * 32];
        float nb = fptr[(size_t)(t4 + 1) * 32];
        float nc = fptr[(size_t)(t4 + 2) * 32];
        float nd = fptr[(size_t)(t4 + 3) * 32];
        VSTEP(t + 0, fa);
        VSTEP(t + 1, fb);
        VSTEP(t + 2, fc);
        VSTEP(t + 3, fd);
        fa = na; fb = nb; fc = nc; fd = nd;
    }
#undef VSTEP

    float term = vcur + trans[31 * 32 + n];
    int idxv = n;
#pragma unroll
    for (int off = 1; off < 32; off <<= 1) {
        float ot = __shfl_xor(term, off);
        int   oi = __shfl_xor(idxv, off);
        if (ot > term || (ot == term && oi < idxv)) { term = ot; idxv = oi; }
    }
    if (l == 0) { out[0] = term; best_ws[0] = idxv; }
}

// ---------------------------------------------------------------- backtrace, 3 phases (proven)
__global__ void bt_chunks(const unsigned char* __restrict__ bp, unsigned char* __restrict__ G) {
    __shared__ unsigned char lbp[32][32];
    int c = blockIdx.x, tid = threadIdx.x;   // 64 threads
    reinterpret_cast<int4*>(lbp)[tid] = reinterpret_cast<const int4*>(bp + (size_t)c * 1024)[tid];
    __syncthreads();
    if (tid < 32) {
        int cur = tid;
#pragma unroll 8
        for (int i = 31; i >= 0; --i) cur = lbp[i][cur];
        G[c * 32 + tid] = (unsigned char)cur;
    }
}
__global__ void bt_boundaries(const unsigned char* __restrict__ G, const int* __restrict__ best,
                              unsigned char* __restrict__ E) {
    __shared__ unsigned char lG[256 * 32];
    int tid = threadIdx.x;                   // 256 threads
    reinterpret_cast<int4*>(lG)[tid]       = reinterpret_cast<const int4*>(G)[tid];
    reinterpret_cast<int4*>(lG)[256 + tid] = reinterpret_cast<const int4*>(G)[256 + tid];
    __syncthreads();
    if (tid == 0) {
        int e = *best;
        E[255] = (unsigned char)e;
        for (int ch = 255; ch >= 1; --ch) { e = lG[ch * 32 + e]; E[ch - 1] = (unsigned char)e; }
    }
}
__global__ void bt_emit(const unsigned char* __restrict__ bp, const unsigned char* __restrict__ E,
                        float* __restrict__ out) {
    __shared__ unsigned char lbp[32][32];
    int c = blockIdx.x, tid = threadIdx.x;   // 64 threads
    reinterpret_cast<int4*>(lbp)[tid] = reinterpret_cast<const int4*>(bp + (size_t)c * 1024)[tid];
    __syncthreads();
    if (tid == 0) {
        int tag = E[c];
        for (int i = 31; i >= 0; --i) {
            out[1 + (size_t)c * 32 + i] = (float)tag;
            tag = lbp[i][tag];
        }
    }
}

// ---------------------------------------------------------------- launch
extern "C" void kernel_launch(void* const* d_in, const int* in_sizes, int n_in,
                              void* d_out, int out_size, void* d_ws, size_t ws_size,
                              hipStream_t stream)
{
    const int*   sentence = (const int*)d_in[0];
    const float* emb      = (const float*)d_in[1];
    const float* w_ih_f   = (const float*)d_in[2];
    const float* w_hh_f   = (const float*)d_in[3];
    const float* b_ih_f   = (const float*)d_in[4];
    const float* b_hh_f   = (const float*)d_in[5];
    const float* w_ih_r   = (const float*)d_in[6];
    const float* w_hh_r   = (const float*)d_in[7];
    const float* b_ih_r   = (const float*)d_in[8];
    const float* b_hh_r   = (const float*)d_in[9];
    const float* w_out    = (const float*)d_in[10];
    const float* b_out    = (const float*)d_in[11];
    const float* trans    = (const float*)d_in[12];
    (void)in_sizes; (void)n_in; (void)out_size; (void)ws_size;

    char* ws = (char*)d_ws;
    size_t off = 0;
    auto alloc = [&](size_t bytes) -> void* {
        void* p = (void*)(ws + off);
        off += (bytes + 255) & ~(size_t)255;
        return p;
    };
    float* gin_f   = (float*)alloc((size_t)SEQ * G4 * 4);          // 32 MiB
    float* gin_r   = (float*)alloc((size_t)SEQ * G4 * 4);          // 32 MiB
    float* hcomp_f = (float*)alloc((size_t)(SEQ + 1) * HD * 4);    // 8 MiB
    float* hcomp_r = (float*)alloc((size_t)(SEQ + 1) * HD * 4);    // 8 MiB
    float* wt_f    = (float*)alloc((size_t)EMBD * G4 * 4);         // 1 MiB
    float* wt_r    = (float*)alloc((size_t)EMBD * G4 * 4);         // 1 MiB
    float* bs_f    = (float*)alloc(G4 * 4);
    float* bs_r    = (float*)alloc(G4 * 4);
    unsigned* wq   = (unsigned*)alloc(2 * 65536 * 4);              // 512 KiB
    float* fac     = (float*)alloc(2 * 1024 * 4);
    float* feats   = (float*)alloc((size_t)SEQ * 32 * 4);          // 1 MiB
    unsigned char* bp = (unsigned char*)alloc((size_t)SEQ * 32);   // 256 KiB
    unsigned char* G  = (unsigned char*)alloc(256 * 32);           // 8 KiB
    unsigned char* E  = (unsigned char*)alloc(256);
    int* best_ws      = (int*)alloc(256);

    bias_kernel<<<1, 256, 0, stream>>>(b_ih_f, b_hh_f, b_ih_r, b_hh_r, bs_f, bs_r);
    wtrans_kernel<<<64, 256, 0, stream>>>(w_ih_f, w_ih_r, wt_f, wt_r);
    wquant_kernel<<<2048, 64, 0, stream>>>(w_hh_f, w_hh_r, wq, fac);
    gin_kernel<<<SEQ / 32, 256, 0, stream>>>(sentence, emb, wt_f, wt_r, bs_f, bs_r,
                                             gin_f, gin_r);
    lstm_kernel<<<2, 1024, 0, stream>>>(wq, fac, gin_f, gin_r, hcomp_f, hcomp_r);
    feats_kernel<<<SEQ / 256, 256, 0, stream>>>(hcomp_f, hcomp_r, w_out, b_out, feats);
    viterbi_dp<<<1, 64, 0, stream>>>(feats, trans, bp, (float*)d_out, best_ws);
    bt_chunks<<<256, 64, 0, stream>>>(bp, G);
    bt_boundaries<<<1, 256, 0, stream>>>(G, best_ws, E);
    bt_emit<<<256, 64, 0, stream>>>(bp, E, (float*)d_out);
}

// Round 13
// 11041.434 us; speedup vs baseline: 1.4303x; 1.0556x over previous
//
#include <hip/hip_runtime.h>

// BiLSTM-CRF forward on MI355X.
//   bias:    bias sums.
//   wtrans:  LDS-tiled transpose of W_ih to [k][row].
//   wquant:  per-row int8 quantization of W_hh -> QUAD-QUARTER layout:
//            wq[dir][r*16+j][u*4+g] packs W[row(r,u)][g*64+4j .. +3].
//   gin:     embedding gather + input projection -> gin[t][rp] (rp=u*4+gate).
//   lstm:    2 blocks x 1024 threads (16 waves, 4/SIMD). R13 change: the
//            per-step __syncthreads() (which drains vmcnt(0) -> serializes the
//            gin HBM prefetch + hcomp store ack into EVERY step) is replaced
//            by a raw "s_waitcnt lgkmcnt(0); s_barrier" (LDS-only drain).
//            Global loads/stores now float across steps; h LDS visibility is
//            still guaranteed (ds_write retires under lgkmcnt before barrier).
//   feats:   [hf,hr] @ w_out^T + b_out.
//   viterbi: register-resident single-wave DP (proven) + 3-phase backtrace.

#define SEQ  8192
#define EMBD 256
#define HD   256
#define G4   1024
#define NEGV -10000.0f

#if __has_builtin(__builtin_amdgcn_sdot4)
__device__ __forceinline__ int SDOT4(unsigned a, unsigned b, int c) {
    return __builtin_amdgcn_sdot4((int)a, (int)b, c, false);
}
#else
__device__ __forceinline__ int SDOT4(unsigned a, unsigned b, int c) {
#pragma unroll
    for (int i = 0; i < 4; ++i) {
        int ai = (int)(a << (24 - 8 * i)) >> 24;
        int bi = (int)(b << (24 - 8 * i)) >> 24;
        c += ai * bi;
    }
    return c;
}
#endif

// LDS-only barrier: ds ops drained (h visibility), global ops stay in flight.
__device__ __forceinline__ void lds_barrier() {
    asm volatile("s_waitcnt lgkmcnt(0)\n\ts_barrier" ::: "memory");
}

// DPP quad_perm (VALU pipe)
template <int CTRL>
__device__ __forceinline__ float dpp_bcast(float x) {
    return __int_as_float(
        __builtin_amdgcn_mov_dpp(__float_as_int(x), CTRL, 0xf, 0xf, true));
}
template <int CTRL>
__device__ __forceinline__ int idpp(int x) {
    return __builtin_amdgcn_mov_dpp(x, CTRL, 0xf, 0xf, true);
}

// ---------------------------------------------------------------- bias sums
__global__ void bias_kernel(const float* __restrict__ b_ih_f, const float* __restrict__ b_hh_f,
                            const float* __restrict__ b_ih_r, const float* __restrict__ b_hh_r,
                            float* __restrict__ bs_f, float* __restrict__ bs_r) {
    int i = threadIdx.x;
#pragma unroll
    for (int m = 0; m < 4; ++m) {
        int row = i + 256 * m;
        bs_f[row] = b_ih_f[row] + b_hh_f[row];
        bs_r[row] = b_ih_r[row] + b_hh_r[row];
    }
}

// ---------------------------------------------------------------- W_ih transpose (tiled)
__global__ __launch_bounds__(256) void wtrans_kernel(
    const float* __restrict__ w_ih_f, const float* __restrict__ w_ih_r,
    float* __restrict__ wt_f, float* __restrict__ wt_r) {
    __shared__ float tile[32][257];
    int mat = blockIdx.x & 1;
    int r0  = (blockIdx.x >> 1) << 5;          // 0,32,...,992
    const float* src = mat ? w_ih_r : w_ih_f;
    float*       dst = mat ? wt_r   : wt_f;
    int tid = threadIdx.x;
    for (int r = 0; r < 32; ++r)
        tile[r][tid] = src[(size_t)(r0 + r) * EMBD + tid];
    __syncthreads();
    int row = tid & 31, kq = tid >> 5;
    for (int kb = 0; kb < EMBD; kb += 8) {
        int k = kb + kq;
        dst[(size_t)k * G4 + r0 + row] = tile[row][k];
    }
}

// ---------------------------------------------------------------- W_hh int8 quantization
// 2048 blocks x 64 threads: dir=b>>10, rp=b&1023 (rp=u*4+r, original row
// = r*256+u). Thread l: j=l&15, g=l>>4. QUAD-QUARTER layout:
// wq[dir][(r*16+j)*1024 + u*4+g] = pack(W[row][g*64+4j .. +3]).
__global__ __launch_bounds__(64) void wquant_kernel(
    const float* __restrict__ w_hh_f, const float* __restrict__ w_hh_r,
    unsigned* __restrict__ wq, float* __restrict__ fac)
{
    int b = blockIdx.x;
    int dir = b >> 10, rp = b & 1023;
    int u = rp >> 2, r = rp & 3;
    int row = r * 256 + u;
    int l = threadIdx.x;
    int j = l & 15, g = l >> 4;
    const float* Wr = (dir ? w_hh_r : w_hh_f) + (size_t)row * HD;
    float4 v = reinterpret_cast<const float4*>(Wr)[g * 16 + j];   // k = g*64+4j
    float m = fmaxf(fmaxf(fabsf(v.x), fabsf(v.y)), fmaxf(fabsf(v.z), fabsf(v.w)));
#pragma unroll
    for (int off = 1; off < 64; off <<= 1) m = fmaxf(m, __shfl_xor(m, off));
    m = fmaxf(m, 1e-20f);
    float inv = 127.f / m;
    int q0 = (int)rintf(v.x * inv), q1 = (int)rintf(v.y * inv);
    int q2 = (int)rintf(v.z * inv), q3 = (int)rintf(v.w * inv);
    unsigned pk = (unsigned)(q0 & 0xff) | ((unsigned)(q1 & 0xff) << 8) |
                  ((unsigned)(q2 & 0xff) << 16) | ((unsigned)(q3 & 0xff) << 24);
    wq[(size_t)dir * 65536 + (size_t)(r * 16 + j) * 1024 + u * 4 + g] = pk;
    if (l == 0) fac[dir * 1024 + rp] = m / (127.f * 127.f);   // dequant scale
}

// ---------------------------------------------------------------- input projection
// writes gin[t][rp] with rp = u*4+gate (bias included)
__global__ __launch_bounds__(256) void gin_kernel(
    const int* __restrict__ sentence, const float* __restrict__ emb,
    const float* __restrict__ wt_f, const float* __restrict__ wt_r,
    const float* __restrict__ bs_f, const float* __restrict__ bs_r,
    float* __restrict__ gin_f, float* __restrict__ gin_r)
{
    __shared__ float x_lds[32][EMBD];
    __shared__ int   sid_lds[32];
    int t0  = blockIdx.x * 32;
    int tid = threadIdx.x;
    if (tid < 32) sid_lds[tid] = sentence[t0 + tid];
    __syncthreads();
    for (int i = 0; i < 32; ++i)
        x_lds[i][tid] = emb[(size_t)sid_lds[i] * EMBD + tid];
    __syncthreads();

    float bsv[8];
#pragma unroll
    for (int m = 0; m < 4; ++m) bsv[m]     = bs_f[tid + 256 * m];
#pragma unroll
    for (int m = 0; m < 4; ++m) bsv[4 + m] = bs_r[tid + 256 * m];

    for (int tsub = 0; tsub < 4; ++tsub) {
        float acc[8][8];
#pragma unroll
        for (int m = 0; m < 8; ++m)
#pragma unroll
            for (int j = 0; j < 8; ++j) acc[m][j] = bsv[m];

        for (int k = 0; k < EMBD; ++k) {
            float xv[8];
#pragma unroll
            for (int j = 0; j < 8; ++j) xv[j] = x_lds[tsub * 8 + j][k];
#pragma unroll
            for (int m = 0; m < 8; ++m) {
                float wv = (m < 4) ? wt_f[(size_t)k * G4 + tid + 256 * m]
                                   : wt_r[(size_t)k * G4 + tid + 256 * (m - 4)];
#pragma unroll
                for (int j = 0; j < 8; ++j) acc[m][j] = fmaf(wv, xv[j], acc[m][j]);
            }
        }
#pragma unroll
        for (int m = 0; m < 8; ++m) {
            int rp = tid * 4 + (m & 3);        // u = tid, gate = m&3
#pragma unroll
            for (int j = 0; j < 8; ++j) {
                int t = t0 + tsub * 8 + j;
                if (m < 4) gin_f[(size_t)t * G4 + rp] = acc[m][j];
                else       gin_r[(size_t)(SEQ - 1 - t) * G4 + rp] = acc[m][j];
            }
        }
    }
}

// ---------------------------------------------------------------- single-CU LSTM per direction
// 2 blocks x 1024 threads (16 waves, 4/SIMD). Thread tid=(u=tid>>2, g=tid&3):
// holds quad u's 4 rows over k-quarter g (w[64]); reads its quarter of h.
__global__ __launch_bounds__(1024, 4) void lstm_kernel(
    const unsigned* __restrict__ wq, const float* __restrict__ fac,
    const float* __restrict__ gin_f, const float* __restrict__ gin_r,
    float* __restrict__ hcomp_f, float* __restrict__ hcomp_r)
{
    int dir = blockIdx.x;
    const float* gin   = dir ? gin_r   : gin_f;
    float*       hcomp = dir ? hcomp_r : hcomp_f;
    int tid = threadIdx.x;
    int g   = tid & 3;
    int u   = tid >> 2;                        // 0..255
    bool q0 = (g == 0);

    unsigned w[64];                            // w[r*16+j]: row r, quarter-dword j
    {
        const unsigned* base = wq + (size_t)dir * 65536;
#pragma unroll
        for (int j = 0; j < 64; ++j) w[j] = base[(size_t)j * 1024 + tid];
    }
    float4 fac4 = *reinterpret_cast<const float4*>(&fac[dir * 1024 + (u << 2)]);

    __shared__ unsigned hq[2][64];             // int8-packed h, double-buffered
    if (tid < 128) ((unsigned*)hq)[tid] = 0u;  // h(0) = 0 (both buffers)

    // uniform per-gate activation: sigmoid (a=1,b=-1,c=0); tanh=2*sigm(2x)-1
    float aa = (g == 2) ? 2.f : 1.f;
    float bb = (g == 2) ? -2.f : -1.f;
    float cc = (g == 2) ? -1.f : 0.f;
    float c = 0.f;

    float g0 = gin[tid];
    float g1 = gin[G4 + tid];
    __syncthreads();                           // once, pre-loop: full drain OK

    for (int t = 0; t < SEQ; ++t) {
        size_t pf = (size_t)((t + 2 < SEQ) ? t + 2 : SEQ - 1) * G4;
        float g2 = gin[pf + tid];              // distance-2 prefetch (floats across barriers now)

        // own k-quarter of h: 4 x ds_read_b128 at byte g*64+16i
        const uint4* hb =
            reinterpret_cast<const uint4*>((const char*)hq[t & 1] + g * 64);
        uint4 h4[4];
#pragma unroll
        for (int i = 0; i < 4; ++i) h4[i] = hb[i];

        int s0 = 0, s1 = 0, s2 = 0, s3 = 0;    // partials for quad rows 0..3
#pragma unroll
        for (int i = 0; i < 4; ++i) {
            s0 = SDOT4(w[0 * 16 + 4 * i + 0], h4[i].x, s0);
            s1 = SDOT4(w[1 * 16 + 4 * i + 0], h4[i].x, s1);
            s2 = SDOT4(w[2 * 16 + 4 * i + 0], h4[i].x, s2);
            s3 = SDOT4(w[3 * 16 + 4 * i + 0], h4[i].x, s3);
            s0 = SDOT4(w[0 * 16 + 4 * i + 1], h4[i].y, s0);
            s1 = SDOT4(w[1 * 16 + 4 * i + 1], h4[i].y, s1);
            s2 = SDOT4(w[2 * 16 + 4 * i + 1], h4[i].y, s2);
            s3 = SDOT4(w[3 * 16 + 4 * i + 1], h4[i].y, s3);
            s0 = SDOT4(w[0 * 16 + 4 * i + 2], h4[i].z, s0);
            s1 = SDOT4(w[1 * 16 + 4 * i + 2], h4[i].z, s1);
            s2 = SDOT4(w[2 * 16 + 4 * i + 2], h4[i].z, s2);
            s3 = SDOT4(w[3 * 16 + 4 * i + 2], h4[i].z, s3);
            s0 = SDOT4(w[0 * 16 + 4 * i + 3], h4[i].w, s0);
            s1 = SDOT4(w[1 * 16 + 4 * i + 3], h4[i].w, s1);
            s2 = SDOT4(w[2 * 16 + 4 * i + 3], h4[i].w, s2);
            s3 = SDOT4(w[3 * 16 + 4 * i + 3], h4[i].w, s3);
        }
        // exact int quad all-reduce (VALU DPP): every lane gets all 4 row sums
        int r0 = s0 + idpp<0xB1>(s0); r0 += idpp<0x4E>(r0);
        int r1 = s1 + idpp<0xB1>(s1); r1 += idpp<0x4E>(r1);
        int r2 = s2 + idpp<0xB1>(s2); r2 += idpp<0x4E>(r2);
        int r3 = s3 + idpp<0xB1>(s3); r3 += idpp<0x4E>(r3);

        int   ps = (g == 0) ? r0 : (g == 1) ? r1 : (g == 2) ? r2 : r3;
        float fs = (g == 0) ? fac4.x : (g == 1) ? fac4.y : (g == 2) ? fac4.z : fac4.w;

        float p   = fmaf((float)ps, fs, g0);
        float act = aa / (1.f + __expf(bb * p)) + cc;      // this row's gate act

        float xf = dpp_bcast<0x55>(act);       // f-gate (quad lane 1)
        float xg = dpp_bcast<0xAA>(act);       // g-gate (quad lane 2)
        float xo = dpp_bcast<0xFF>(act);       // o-gate (quad lane 3)

        if (q0) {                              // act = i; one lane per unit
            c = xf * c + act * xg;
            float h = xo * (2.f / (1.f + __expf(-2.f * c)) - 1.f);
            hcomp[(size_t)(t + 1) * HD + u] = h;   // fire-and-forget store
            ((char*)hq[(t + 1) & 1])[u] = (char)(int)rintf(h * 127.f);
        }
        lds_barrier();                         // LDS-only drain: vmcnt ops stay in flight
        g0 = g1; g1 = g2;
    }
}

// ---------------------------------------------------------------- feats = [hf,hr] @ w_out^T + b
__global__ __launch_bounds__(256) void feats_kernel(
    const float* __restrict__ hf_buf, const float* __restrict__ hr_buf,
    const float* __restrict__ w_out, const float* __restrict__ b_out,
    float* __restrict__ feats)
{
    __shared__ __align__(16) float wt_lds[256][36];
    int tid = threadIdx.x;
    int t   = blockIdx.x * 256 + tid;

    float acc[32];
#pragma unroll
    for (int g = 0; g < 32; ++g) acc[g] = b_out[g];

    for (int half = 0; half < 2; ++half) {
        __syncthreads();
        for (int tag = 0; tag < 32; ++tag)
            wt_lds[tid][tag] = w_out[tag * 512 + half * 256 + tid];
        __syncthreads();

        const float* hsrc = (half == 0) ? &hf_buf[(size_t)(t + 1) * HD]
                                        : &hr_buf[(size_t)(SEQ - t) * HD];
        for (int k = 0; k < 256; k += 4) {
            float4 hv = *reinterpret_cast<const float4*>(&hsrc[k]);
#pragma unroll
            for (int kk = 0; kk < 4; ++kk) {
                float hx = (kk == 0) ? hv.x : (kk == 1) ? hv.y : (kk == 2) ? hv.z : hv.w;
#pragma unroll
                for (int qq = 0; qq < 8; ++qq) {
                    float4 wv = *reinterpret_cast<const float4*>(&wt_lds[k + kk][4 * qq]);
                    acc[4 * qq + 0] = fmaf(hx, wv.x, acc[4 * qq + 0]);
                    acc[4 * qq + 1] = fmaf(hx, wv.y, acc[4 * qq + 1]);
                    acc[4 * qq + 2] = fmaf(hx, wv.z, acc[4 * qq + 2]);
                    acc[4 * qq + 3] = fmaf(hx, wv.w, acc[4 * qq + 3]);
                }
            }
        }
    }
#pragma unroll
    for (int qq = 0; qq < 8; ++qq) {
        float4 o;
        o.x = acc[4 * qq + 0]; o.y = acc[4 * qq + 1];
        o.z = acc[4 * qq + 2]; o.w = acc[4 * qq + 3];
        *reinterpret_cast<float4*>(&feats[(size_t)t * 32 + 4 * qq]) = o;
    }
}

// ---------------------------------------------------------------- viterbi DP, register-resident
__global__ void viterbi_dp(const float* __restrict__ feats,
                           const float* __restrict__ trans,
                           unsigned char* __restrict__ bp,
                           float* __restrict__ out, int* __restrict__ best_ws)
{
    int l = threadIdx.x;
    int n = l & 31, h = l >> 5;

    float Tn[16];
    int   addr[16], pidx[16];
#pragma unroll
    for (int j = 0; j < 16; ++j) {
        Tn[j]   = trans[n * 32 + 16 * h + j];
        addr[j] = (16 * h + j) * 4;
        pidx[j] = 16 * h + j;
    }

    float vcur = (n == 30) ? 0.0f : NEGV;      // START = 30

    const float* fptr = feats + n;
    float fa = fptr[0], fb = fptr[32], fc = fptr[64], fd = fptr[96];

#define VSTEP(TT, FV)                                                          \
    {                                                                          \
        float cand[16]; int idx[16];                                           \
        _Pragma("unroll")                                                      \
        for (int j = 0; j < 16; ++j) {                                         \
            float pv = __int_as_float(                                         \
                __builtin_amdgcn_ds_bpermute(addr[j], __float_as_int(vcur)));  \
            cand[j] = pv + Tn[j];                                              \
            idx[j] = pidx[j];                                                  \
        }                                                                      \
        _Pragma("unroll")                                                      \
        for (int st = 1; st < 16; st <<= 1)                                    \
            _Pragma("unroll")                                                  \
            for (int p = 0; p < 16; p += 2 * st) {                             \
                bool rgt = cand[p + st] > cand[p];   /* left wins ties */      \
                cand[p] = rgt ? cand[p + st] : cand[p];                        \
                idx[p]  = rgt ? idx[p + st]  : idx[p];                         \
            }                                                                  \
        float ob = __shfl_xor(cand[0], 32);                                    \
        int   oa = __shfl_xor(idx[0], 32);                                     \
        bool useOther = h ? (ob >= cand[0]) : (ob > cand[0]);                  \
        float best = useOther ? ob : cand[0];                                  \
        int   aarg = useOther ? oa : idx[0];                                   \
        if (h == 0) bp[(size_t)(TT) * 32 + n] = (unsigned char)aarg;           \
        vcur = best + (FV);                                                    \
    }

    for (int t = 0; t < SEQ; t += 4) {
        int t4 = (t + 4 < SEQ) ? (t + 4) : (SEQ - 4);
        float na = fptr[(size_t)(t4 + 0) * 32];
        float nb = fptr[(size_t)(t4 + 1) * 32];
        float nc = fptr[(size_t)(t4 + 2) * 32];
        float nd = fptr[(size_t)(t4 + 3) * 32];
        VSTEP(t + 0, fa);
        VSTEP(t + 1, fb);
        VSTEP(t + 2, fc);
        VSTEP(t + 3, fd);
        fa = na; fb = nb; fc = nc; fd = nd;
    }
#undef VSTEP

    float term = vcur + trans[31 * 32 + n];
    int idxv = n;
#pragma unroll
    for (int off = 1; off < 32; off <<= 1) {
        float ot = __shfl_xor(term, off);
        int   oi = __shfl_xor(idxv, off);
        if (ot > term || (ot == term && oi < idxv)) { term = ot; idxv = oi; }
    }
    if (l == 0) { out[0] = term; best_ws[0] = idxv; }
}

// ---------------------------------------------------------------- backtrace, 3 phases (proven)
__global__ void bt_chunks(const unsigned char* __restrict__ bp, unsigned char* __restrict__ G) {
    __shared__ unsigned char lbp[32][32];
    int c = blockIdx.x, tid = threadIdx.x;   // 64 threads
    reinterpret_cast<int4*>(lbp)[tid] = reinterpret_cast<const int4*>(bp + (size_t)c * 1024)[tid];
    __syncthreads();
    if (tid < 32) {
        int cur = tid;
#pragma unroll 8
        for (int i = 31; i >= 0; --i) cur = lbp[i][cur];
        G[c * 32 + tid] = (unsigned char)cur;
    }
}
__global__ void bt_boundaries(const unsigned char* __restrict__ G, const int* __restrict__ best,
                              unsigned char* __restrict__ E) {
    __shared__ unsigned char lG[256 * 32];
    int tid = threadIdx.x;                   // 256 threads
    reinterpret_cast<int4*>(lG)[tid]       = reinterpret_cast<const int4*>(G)[tid];
    reinterpret_cast<int4*>(lG)[256 + tid] = reinterpret_cast<const int4*>(G)[256 + tid];
    __syncthreads();
    if (tid == 0) {
        int e = *best;
        E[255] = (unsigned char)e;
        for (int ch = 255; ch >= 1; --ch) { e = lG[ch * 32 + e]; E[ch - 1] = (unsigned char)e; }
    }
}
__global__ void bt_emit(const unsigned char* __restrict__ bp, const unsigned char* __restrict__ E,
                        float* __restrict__ out) {
    __shared__ unsigned char lbp[32][32];
    int c = blockIdx.x, tid = threadIdx.x;   // 64 threads
    reinterpret_cast<int4*>(lbp)[tid] = reinterpret_cast<const int4*>(bp + (size_t)c * 1024)[tid];
    __syncthreads();
    if (tid == 0) {
        int tag = E[c];
        for (int i = 31; i >= 0; --i) {
            out[1 + (size_t)c * 32 + i] = (float)tag;
            tag = lbp[i][tag];
        }
    }
}

// ---------------------------------------------------------------- launch
extern "C" void kernel_launch(void* const* d_in, const int* in_sizes, int n_in,
                              void* d_out, int out_size, void* d_ws, size_t ws_size,
                              hipStream_t stream)
{
    const int*   sentence = (const int*)d_in[0];
    const float* emb      = (const float*)d_in[1];
    const float* w_ih_f   = (const float*)d_in[2];
    const float* w_hh_f   = (const float*)d_in[3];
    const float* b_ih_f   = (const float*)d_in[4];
    const float* b_hh_f   = (const float*)d_in[5];
    const float* w_ih_r   = (const float*)d_in[6];
    const float* w_hh_r   = (const float*)d_in[7];
    const float* b_ih_r   = (const float*)d_in[8];
    const float* b_hh_r   = (const float*)d_in[9];
    const float* w_out    = (const float*)d_in[10];
    const float* b_out    = (const float*)d_in[11];
    const float* trans    = (const float*)d_in[12];
    (void)in_sizes; (void)n_in; (void)out_size; (void)ws_size;

    char* ws = (char*)d_ws;
    size_t off = 0;
    auto alloc = [&](size_t bytes) -> void* {
        void* p = (void*)(ws + off);
        off += (bytes + 255) & ~(size_t)255;
        return p;
    };
    float* gin_f   = (float*)alloc((size_t)SEQ * G4 * 4);          // 32 MiB
    float* gin_r   = (float*)alloc((size_t)SEQ * G4 * 4);          // 32 MiB
    float* hcomp_f = (float*)alloc((size_t)(SEQ + 1) * HD * 4);    // 8 MiB
    float* hcomp_r = (float*)alloc((size_t)(SEQ + 1) * HD * 4);    // 8 MiB
    float* wt_f    = (float*)alloc((size_t)EMBD * G4 * 4);         // 1 MiB
    float* wt_r    = (float*)alloc((size_t)EMBD * G4 * 4);         // 1 MiB
    float* bs_f    = (float*)alloc(G4 * 4);
    float* bs_r    = (float*)alloc(G4 * 4);
    unsigned* wq   = (unsigned*)alloc(2 * 65536 * 4);              // 512 KiB
    float* fac     = (float*)alloc(2 * 1024 * 4);
    float* feats   = (float*)alloc((size_t)SEQ * 32 * 4);          // 1 MiB
    unsigned char* bp = (unsigned char*)alloc((size_t)SEQ * 32);   // 256 KiB
    unsigned char* G  = (unsigned char*)alloc(256 * 32);           // 8 KiB
    unsigned char* E  = (unsigned char*)alloc(256);
    int* best_ws      = (int*)alloc(256);

    bias_kernel<<<1, 256, 0, stream>>>(b_ih_f, b_hh_f, b_ih_r, b_hh_r, bs_f, bs_r);
    wtrans_kernel<<<64, 256, 0, stream>>>(w_ih_f, w_ih_r, wt_f, wt_r);
    wquant_kernel<<<2048, 64, 0, stream>>>(w_hh_f, w_hh_r, wq, fac);
    gin_kernel<<<SEQ / 32, 256, 0, stream>>>(sentence, emb, wt_f, wt_r, bs_f, bs_r,
                                             gin_f, gin_r);
    lstm_kernel<<<2, 1024, 0, stream>>>(wq, fac, gin_f, gin_r, hcomp_f, hcomp_r);
    feats_kernel<<<SEQ / 256, 256, 0, stream>>>(hcomp_f, hcomp_r, w_out, b_out, feats);
    viterbi_dp<<<1, 64, 0, stream>>>(feats, trans, bp, (float*)d_out, best_ws);
    bt_chunks<<<256, 64, 0, stream>>>(bp, G);
    bt_boundaries<<<1, 256, 0, stream>>>(G, best_ws, E);
    bt_emit<<<256, 64, 0, stream>>>(bp, E, (float*)d_out);
}

// Round 14
// 8927.602 us; speedup vs baseline: 1.7689x; 1.2368x over previous
//
#include <hip/hip_runtime.h>

// BiLSTM-CRF forward on MI355X.
//   bias:    bias sums.
//   wtrans:  LDS-tiled transpose of W_ih to [k][row].
//   wquant:  per-row int8 quantization of W_hh (quad-quarter layout).
//   gin:     embedding gather + input projection -> gin[t][rp] (rp=u*4+gate).
//   lstm:    2 blocks x 1024 threads (16 waves), LDS-only barrier (R13, proven
//            8.43ms). Untouched this round.
//   feats:   [hf,hr] @ w_out^T + b_out.
//   viterbi (R14): max-plus chunk-composition scan replaces the 8192-step
//            single-wave DP (~1.4ms -> ~0.1ms):
//              vp_chunks: per 32-step chunk, compose the (max,+) step maps
//                         into a 32x32 matrix P_c (32 basis columns evolved
//                         by 16 wave-engines; max is order-exact).
//              vp_scan:   1 wave, 256 boundary matvecs v_{c+1}=P_c (+) v_c,
//                         stores chunk-start vectors + terminal argmax.
//              vp_replay: 256 parallel blocks re-run the EXACT sequential
//                         step (reference tie-break) from each boundary
//                         vector, emitting backpointers.
//            Then the proven 3-phase parallel backtrace.

#define SEQ  8192
#define EMBD 256
#define HD   256
#define G4   1024
#define NEGV -10000.0f
#define NCH  256          // chunks
#define CLEN 32           // steps per chunk

#if __has_builtin(__builtin_amdgcn_sdot4)
__device__ __forceinline__ int SDOT4(unsigned a, unsigned b, int c) {
    return __builtin_amdgcn_sdot4((int)a, (int)b, c, false);
}
#else
__device__ __forceinline__ int SDOT4(unsigned a, unsigned b, int c) {
#pragma unroll
    for (int i = 0; i < 4; ++i) {
        int ai = (int)(a << (24 - 8 * i)) >> 24;
        int bi = (int)(b << (24 - 8 * i)) >> 24;
        c += ai * bi;
    }
    return c;
}
#endif

// LDS-only barrier: ds ops drained (h visibility), global ops stay in flight.
__device__ __forceinline__ void lds_barrier() {
    asm volatile("s_waitcnt lgkmcnt(0)\n\ts_barrier" ::: "memory");
}

// DPP quad_perm (VALU pipe)
template <int CTRL>
__device__ __forceinline__ float dpp_bcast(float x) {
    return __int_as_float(
        __builtin_amdgcn_mov_dpp(__float_as_int(x), CTRL, 0xf, 0xf, true));
}
template <int CTRL>
__device__ __forceinline__ int idpp(int x) {
    return __builtin_amdgcn_mov_dpp(x, CTRL, 0xf, 0xf, true);
}

__device__ __forceinline__ float bperm(int addr, float v) {
    return __int_as_float(__builtin_amdgcn_ds_bpermute(addr, __float_as_int(v)));
}

// ---------------------------------------------------------------- bias sums
__global__ void bias_kernel(const float* __restrict__ b_ih_f, const float* __restrict__ b_hh_f,
                            const float* __restrict__ b_ih_r, const float* __restrict__ b_hh_r,
                            float* __restrict__ bs_f, float* __restrict__ bs_r) {
    int i = threadIdx.x;
#pragma unroll
    for (int m = 0; m < 4; ++m) {
        int row = i + 256 * m;
        bs_f[row] = b_ih_f[row] + b_hh_f[row];
        bs_r[row] = b_ih_r[row] + b_hh_r[row];
    }
}

// ---------------------------------------------------------------- W_ih transpose (tiled)
__global__ __launch_bounds__(256) void wtrans_kernel(
    const float* __restrict__ w_ih_f, const float* __restrict__ w_ih_r,
    float* __restrict__ wt_f, float* __restrict__ wt_r) {
    __shared__ float tile[32][257];
    int mat = blockIdx.x & 1;
    int r0  = (blockIdx.x >> 1) << 5;          // 0,32,...,992
    const float* src = mat ? w_ih_r : w_ih_f;
    float*       dst = mat ? wt_r   : wt_f;
    int tid = threadIdx.x;
    for (int r = 0; r < 32; ++r)
        tile[r][tid] = src[(size_t)(r0 + r) * EMBD + tid];
    __syncthreads();
    int row = tid & 31, kq = tid >> 5;
    for (int kb = 0; kb < EMBD; kb += 8) {
        int k = kb + kq;
        dst[(size_t)k * G4 + r0 + row] = tile[row][k];
    }
}

// ---------------------------------------------------------------- W_hh int8 quantization
// QUAD-QUARTER layout: wq[dir][(r*16+j)*1024 + u*4+g] = pack(W[row][g*64+4j ..]).
__global__ __launch_bounds__(64) void wquant_kernel(
    const float* __restrict__ w_hh_f, const float* __restrict__ w_hh_r,
    unsigned* __restrict__ wq, float* __restrict__ fac)
{
    int b = blockIdx.x;
    int dir = b >> 10, rp = b & 1023;
    int u = rp >> 2, r = rp & 3;
    int row = r * 256 + u;
    int l = threadIdx.x;
    int j = l & 15, g = l >> 4;
    const float* Wr = (dir ? w_hh_r : w_hh_f) + (size_t)row * HD;
    float4 v = reinterpret_cast<const float4*>(Wr)[g * 16 + j];   // k = g*64+4j
    float m = fmaxf(fmaxf(fabsf(v.x), fabsf(v.y)), fmaxf(fabsf(v.z), fabsf(v.w)));
#pragma unroll
    for (int off = 1; off < 64; off <<= 1) m = fmaxf(m, __shfl_xor(m, off));
    m = fmaxf(m, 1e-20f);
    float inv = 127.f / m;
    int q0 = (int)rintf(v.x * inv), q1 = (int)rintf(v.y * inv);
    int q2 = (int)rintf(v.z * inv), q3 = (int)rintf(v.w * inv);
    unsigned pk = (unsigned)(q0 & 0xff) | ((unsigned)(q1 & 0xff) << 8) |
                  ((unsigned)(q2 & 0xff) << 16) | ((unsigned)(q3 & 0xff) << 24);
    wq[(size_t)dir * 65536 + (size_t)(r * 16 + j) * 1024 + u * 4 + g] = pk;
    if (l == 0) fac[dir * 1024 + rp] = m / (127.f * 127.f);   // dequant scale
}

// ---------------------------------------------------------------- input projection
__global__ __launch_bounds__(256) void gin_kernel(
    const int* __restrict__ sentence, const float* __restrict__ emb,
    const float* __restrict__ wt_f, const float* __restrict__ wt_r,
    const float* __restrict__ bs_f, const float* __restrict__ bs_r,
    float* __restrict__ gin_f, float* __restrict__ gin_r)
{
    __shared__ float x_lds[32][EMBD];
    __shared__ int   sid_lds[32];
    int t0  = blockIdx.x * 32;
    int tid = threadIdx.x;
    if (tid < 32) sid_lds[tid] = sentence[t0 + tid];
    __syncthreads();
    for (int i = 0; i < 32; ++i)
        x_lds[i][tid] = emb[(size_t)sid_lds[i] * EMBD + tid];
    __syncthreads();

    float bsv[8];
#pragma unroll
    for (int m = 0; m < 4; ++m) bsv[m]     = bs_f[tid + 256 * m];
#pragma unroll
    for (int m = 0; m < 4; ++m) bsv[4 + m] = bs_r[tid + 256 * m];

    for (int tsub = 0; tsub < 4; ++tsub) {
        float acc[8][8];
#pragma unroll
        for (int m = 0; m < 8; ++m)
#pragma unroll
            for (int j = 0; j < 8; ++j) acc[m][j] = bsv[m];

        for (int k = 0; k < EMBD; ++k) {
            float xv[8];
#pragma unroll
            for (int j = 0; j < 8; ++j) xv[j] = x_lds[tsub * 8 + j][k];
#pragma unroll
            for (int m = 0; m < 8; ++m) {
                float wv = (m < 4) ? wt_f[(size_t)k * G4 + tid + 256 * m]
                                   : wt_r[(size_t)k * G4 + tid + 256 * (m - 4)];
#pragma unroll
                for (int j = 0; j < 8; ++j) acc[m][j] = fmaf(wv, xv[j], acc[m][j]);
            }
        }
#pragma unroll
        for (int m = 0; m < 8; ++m) {
            int rp = tid * 4 + (m & 3);        // u = tid, gate = m&3
#pragma unroll
            for (int j = 0; j < 8; ++j) {
                int t = t0 + tsub * 8 + j;
                if (m < 4) gin_f[(size_t)t * G4 + rp] = acc[m][j];
                else       gin_r[(size_t)(SEQ - 1 - t) * G4 + rp] = acc[m][j];
            }
        }
    }
}

// ---------------------------------------------------------------- single-CU LSTM per direction
// (R13 structure — unchanged, proven 8.43ms)
__global__ __launch_bounds__(1024, 4) void lstm_kernel(
    const unsigned* __restrict__ wq, const float* __restrict__ fac,
    const float* __restrict__ gin_f, const float* __restrict__ gin_r,
    float* __restrict__ hcomp_f, float* __restrict__ hcomp_r)
{
    int dir = blockIdx.x;
    const float* gin   = dir ? gin_r   : gin_f;
    float*       hcomp = dir ? hcomp_r : hcomp_f;
    int tid = threadIdx.x;
    int g   = tid & 3;
    int u   = tid >> 2;                        // 0..255
    bool q0 = (g == 0);

    unsigned w[64];                            // w[r*16+j]: row r, quarter-dword j
    {
        const unsigned* base = wq + (size_t)dir * 65536;
#pragma unroll
        for (int j = 0; j < 64; ++j) w[j] = base[(size_t)j * 1024 + tid];
    }
    float4 fac4 = *reinterpret_cast<const float4*>(&fac[dir * 1024 + (u << 2)]);

    __shared__ unsigned hq[2][64];             // int8-packed h, double-buffered
    if (tid < 128) ((unsigned*)hq)[tid] = 0u;  // h(0) = 0 (both buffers)

    float aa = (g == 2) ? 2.f : 1.f;
    float bb = (g == 2) ? -2.f : -1.f;
    float cc = (g == 2) ? -1.f : 0.f;
    float c = 0.f;

    float g0 = gin[tid];
    float g1 = gin[G4 + tid];
    __syncthreads();                           // once, pre-loop: full drain OK

    for (int t = 0; t < SEQ; ++t) {
        size_t pf = (size_t)((t + 2 < SEQ) ? t + 2 : SEQ - 1) * G4;
        float g2 = gin[pf + tid];              // distance-2 prefetch

        const uint4* hb =
            reinterpret_cast<const uint4*>((const char*)hq[t & 1] + g * 64);
        uint4 h4[4];
#pragma unroll
        for (int i = 0; i < 4; ++i) h4[i] = hb[i];

        int s0 = 0, s1 = 0, s2 = 0, s3 = 0;    // partials for quad rows 0..3
#pragma unroll
        for (int i = 0; i < 4; ++i) {
            s0 = SDOT4(w[0 * 16 + 4 * i + 0], h4[i].x, s0);
            s1 = SDOT4(w[1 * 16 + 4 * i + 0], h4[i].x, s1);
            s2 = SDOT4(w[2 * 16 + 4 * i + 0], h4[i].x, s2);
            s3 = SDOT4(w[3 * 16 + 4 * i + 0], h4[i].x, s3);
            s0 = SDOT4(w[0 * 16 + 4 * i + 1], h4[i].y, s0);
            s1 = SDOT4(w[1 * 16 + 4 * i + 1], h4[i].y, s1);
            s2 = SDOT4(w[2 * 16 + 4 * i + 1], h4[i].y, s2);
            s3 = SDOT4(w[3 * 16 + 4 * i + 1], h4[i].y, s3);
            s0 = SDOT4(w[0 * 16 + 4 * i + 2], h4[i].z, s0);
            s1 = SDOT4(w[1 * 16 + 4 * i + 2], h4[i].z, s1);
            s2 = SDOT4(w[2 * 16 + 4 * i + 2], h4[i].z, s2);
            s3 = SDOT4(w[3 * 16 + 4 * i + 2], h4[i].z, s3);
            s0 = SDOT4(w[0 * 16 + 4 * i + 3], h4[i].w, s0);
            s1 = SDOT4(w[1 * 16 + 4 * i + 3], h4[i].w, s1);
            s2 = SDOT4(w[2 * 16 + 4 * i + 3], h4[i].w, s2);
            s3 = SDOT4(w[3 * 16 + 4 * i + 3], h4[i].w, s3);
        }
        int r0 = s0 + idpp<0xB1>(s0); r0 += idpp<0x4E>(r0);
        int r1 = s1 + idpp<0xB1>(s1); r1 += idpp<0x4E>(r1);
        int r2 = s2 + idpp<0xB1>(s2); r2 += idpp<0x4E>(r2);
        int r3 = s3 + idpp<0xB1>(s3); r3 += idpp<0x4E>(r3);

        int   ps = (g == 0) ? r0 : (g == 1) ? r1 : (g == 2) ? r2 : r3;
        float fs = (g == 0) ? fac4.x : (g == 1) ? fac4.y : (g == 2) ? fac4.z : fac4.w;

        float p   = fmaf((float)ps, fs, g0);
        float act = aa / (1.f + __expf(bb * p)) + cc;      // this row's gate act

        float xf = dpp_bcast<0x55>(act);       // f-gate (quad lane 1)
        float xg = dpp_bcast<0xAA>(act);       // g-gate (quad lane 2)
        float xo = dpp_bcast<0xFF>(act);       // o-gate (quad lane 3)

        if (q0) {                              // act = i; one lane per unit
            c = xf * c + act * xg;
            float h = xo * (2.f / (1.f + __expf(-2.f * c)) - 1.f);
            hcomp[(size_t)(t + 1) * HD + u] = h;   // fire-and-forget store
            ((char*)hq[(t + 1) & 1])[u] = (char)(int)rintf(h * 127.f);
        }
        lds_barrier();                         // LDS-only drain
        g0 = g1; g1 = g2;
    }
}

// ---------------------------------------------------------------- feats = [hf,hr] @ w_out^T + b
__global__ __launch_bounds__(256) void feats_kernel(
    const float* __restrict__ hf_buf, const float* __restrict__ hr_buf,
    const float* __restrict__ w_out, const float* __restrict__ b_out,
    float* __restrict__ feats)
{
    __shared__ __align__(16) float wt_lds[256][36];
    int tid = threadIdx.x;
    int t   = blockIdx.x * 256 + tid;

    float acc[32];
#pragma unroll
    for (int g = 0; g < 32; ++g) acc[g] = b_out[g];

    for (int half = 0; half < 2; ++half) {
        __syncthreads();
        for (int tag = 0; tag < 32; ++tag)
            wt_lds[tid][tag] = w_out[tag * 512 + half * 256 + tid];
        __syncthreads();

        const float* hsrc = (half == 0) ? &hf_buf[(size_t)(t + 1) * HD]
                                        : &hr_buf[(size_t)(SEQ - t) * HD];
        for (int k = 0; k < 256; k += 4) {
            float4 hv = *reinterpret_cast<const float4*>(&hsrc[k]);
#pragma unroll
            for (int kk = 0; kk < 4; ++kk) {
                float hx = (kk == 0) ? hv.x : (kk == 1) ? hv.y : (kk == 2) ? hv.z : hv.w;
#pragma unroll
                for (int qq = 0; qq < 8; ++qq) {
                    float4 wv = *reinterpret_cast<const float4*>(&wt_lds[k + kk][4 * qq]);
                    acc[4 * qq + 0] = fmaf(hx, wv.x, acc[4 * qq + 0]);
                    acc[4 * qq + 1] = fmaf(hx, wv.y, acc[4 * qq + 1]);
                    acc[4 * qq + 2] = fmaf(hx, wv.z, acc[4 * qq + 2]);
                    acc[4 * qq + 3] = fmaf(hx, wv.w, acc[4 * qq + 3]);
                }
            }
        }
    }
#pragma unroll
    for (int qq = 0; qq < 8; ++qq) {
        float4 o;
        o.x = acc[4 * qq + 0]; o.y = acc[4 * qq + 1];
        o.z = acc[4 * qq + 2]; o.w = acc[4 * qq + 3];
        *reinterpret_cast<float4*>(&feats[(size_t)t * 32 + 4 * qq]) = o;
    }
}

// ---------------------------------------------------------------- vp_chunks
// grid NCH x 1024: 16 wave-engines per block; engine w evolves basis columns
// p=w and p=w+16 through the chunk's 32 (max,+) step maps. Max is order-exact.
__global__ __launch_bounds__(1024) void vp_chunks(
    const float* __restrict__ feats, const float* __restrict__ trans,
    float* __restrict__ Pmat)
{
    __shared__ float flds[CLEN * 32];
    int c = blockIdx.x, tid = threadIdx.x;
    flds[tid] = feats[(size_t)c * (CLEN * 32) + tid];
    __syncthreads();

    int l = tid & 63, w = tid >> 6;
    int n = l & 31, h = l >> 5;
    float Tn[16]; int addr[16];
#pragma unroll
    for (int j = 0; j < 16; ++j) {
        Tn[j]   = trans[n * 32 + 16 * h + j];
        addr[j] = (16 * h + j) * 4;
    }
    int pA = w, pB = w + 16;
    float vA = (n == pA) ? 0.f : -1e30f;       // basis columns (max-plus identity)
    float vB = (n == pB) ? 0.f : -1e30f;

    for (int s = 0; s < CLEN; ++s) {
        float fv = flds[s * 32 + n];
        float bA = -3.4e38f, bB = -3.4e38f;
#pragma unroll
        for (int j = 0; j < 16; ++j) {
            bA = fmaxf(bA, bperm(addr[j], vA) + Tn[j]);
            bB = fmaxf(bB, bperm(addr[j], vB) + Tn[j]);
        }
        bA = fmaxf(bA, __shfl_xor(bA, 32));
        bB = fmaxf(bB, __shfl_xor(bB, 32));
        vA = bA + fv;
        vB = bB + fv;
    }
    if (h == 0) {
        Pmat[(size_t)c * 1024 + n * 32 + pA] = vA;
        Pmat[(size_t)c * 1024 + n * 32 + pB] = vB;
    }
}

// ---------------------------------------------------------------- vp_scan
// 1 wave: sequential boundary matvecs v_{c+1}(n) = max_p(P_c(n,p)+v_c(p));
// stores chunk-start vectors; terminal argmax (lowest-index tie-break).
__global__ void vp_scan(const float* __restrict__ Pmat, const float* __restrict__ trans,
                        float* __restrict__ vbound, float* __restrict__ out,
                        int* __restrict__ best_ws)
{
    int l = threadIdx.x;
    int n = l & 31, h = l >> 5;
    int addr[16];
#pragma unroll
    for (int j = 0; j < 16; ++j) addr[j] = (16 * h + j) * 4;

    float vcur = (n == 30) ? 0.0f : NEGV;      // START = 30

    const float* Pr = Pmat + n * 32 + 16 * h;  // row n, this half's 16 cols
    float4 nx0 = reinterpret_cast<const float4*>(Pr)[0];
    float4 nx1 = reinterpret_cast<const float4*>(Pr)[1];
    float4 nx2 = reinterpret_cast<const float4*>(Pr)[2];
    float4 nx3 = reinterpret_cast<const float4*>(Pr)[3];

    for (int c = 0; c < NCH; ++c) {
        float4 p0 = nx0, p1 = nx1, p2 = nx2, p3 = nx3;
        if (c + 1 < NCH) {
            const float* Pn = Pmat + (size_t)(c + 1) * 1024 + n * 32 + 16 * h;
            nx0 = reinterpret_cast<const float4*>(Pn)[0];
            nx1 = reinterpret_cast<const float4*>(Pn)[1];
            nx2 = reinterpret_cast<const float4*>(Pn)[2];
            nx3 = reinterpret_cast<const float4*>(Pn)[3];
        }
        if (h == 0) vbound[c * 32 + n] = vcur;  // v at chunk start

        float pr[16];
        *reinterpret_cast<float4*>(&pr[0])  = p0;
        *reinterpret_cast<float4*>(&pr[4])  = p1;
        *reinterpret_cast<float4*>(&pr[8])  = p2;
        *reinterpret_cast<float4*>(&pr[12]) = p3;

        float best = -3.4e38f;
#pragma unroll
        for (int j = 0; j < 16; ++j)
            best = fmaxf(best, bperm(addr[j], vcur) + pr[j]);
        best = fmaxf(best, __shfl_xor(best, 32));
        vcur = best;
    }

    float term = vcur + trans[31 * 32 + n];    // STOP = 31
    int idxv = n;
#pragma unroll
    for (int off = 1; off < 64; off <<= 1) {
        float ot = __shfl_xor(term, off);
        int   oi = __shfl_xor(idxv, off);
        if (ot > term || (ot == term && oi < idxv)) { term = ot; idxv = oi; }
    }
    if (l == 0) { out[0] = term; best_ws[0] = idxv; }
}

// ---------------------------------------------------------------- vp_replay
// grid NCH x 64: exact sequential DP (reference op order + tie-break) from the
// chunk-start vector, emitting backpointers.
__global__ void vp_replay(const float* __restrict__ feats, const float* __restrict__ trans,
                          const float* __restrict__ vbound, unsigned char* __restrict__ bp)
{
    int c = blockIdx.x;
    int l = threadIdx.x;
    int n = l & 31, h = l >> 5;

    float Tn[16];
    int   addr[16], pidx[16];
#pragma unroll
    for (int j = 0; j < 16; ++j) {
        Tn[j]   = trans[n * 32 + 16 * h + j];
        addr[j] = (16 * h + j) * 4;
        pidx[j] = 16 * h + j;
    }

    float vcur = vbound[c * 32 + n];
    const float* fptr = feats + (size_t)c * (CLEN * 32) + n;
    float fnext = fptr[0];

    for (int s = 0; s < CLEN; ++s) {
        float fcur = fnext;
        if (s + 1 < CLEN) fnext = fptr[(size_t)(s + 1) * 32];

        float cand[16]; int idx[16];
#pragma unroll
        for (int j = 0; j < 16; ++j) {
            cand[j] = bperm(addr[j], vcur) + Tn[j];
            idx[j]  = pidx[j];
        }
        // tournament: prefer LEFT (lower index) on ties — matches jnp.argmax
#pragma unroll
        for (int st = 1; st < 16; st <<= 1)
#pragma unroll
            for (int p = 0; p < 16; p += 2 * st) {
                bool rgt = cand[p + st] > cand[p];
                cand[p] = rgt ? cand[p + st] : cand[p];
                idx[p]  = rgt ? idx[p + st]  : idx[p];
            }
        float ob = __shfl_xor(cand[0], 32);
        int   oa = __shfl_xor(idx[0], 32);
        bool useOther = h ? (ob >= cand[0]) : (ob > cand[0]);  // low half wins ties
        float best = useOther ? ob : cand[0];
        int   aarg = useOther ? oa : idx[0];

        if (h == 0) bp[(size_t)(c * CLEN + s) * 32 + n] = (unsigned char)aarg;
        vcur = best + fcur;
    }
}

// ---------------------------------------------------------------- backtrace, 3 phases (proven)
__global__ void bt_chunks(const unsigned char* __restrict__ bp, unsigned char* __restrict__ G) {
    __shared__ unsigned char lbp[32][32];
    int c = blockIdx.x, tid = threadIdx.x;   // 64 threads
    reinterpret_cast<int4*>(lbp)[tid] = reinterpret_cast<const int4*>(bp + (size_t)c * 1024)[tid];
    __syncthreads();
    if (tid < 32) {
        int cur = tid;
#pragma unroll 8
        for (int i = 31; i >= 0; --i) cur = lbp[i][cur];
        G[c * 32 + tid] = (unsigned char)cur;
    }
}
__global__ void bt_boundaries(const unsigned char* __restrict__ G, const int* __restrict__ best,
                              unsigned char* __restrict__ E) {
    __shared__ unsigned char lG[256 * 32];
    int tid = threadIdx.x;                   // 256 threads
    reinterpret_cast<int4*>(lG)[tid]       = reinterpret_cast<const int4*>(G)[tid];
    reinterpret_cast<int4*>(lG)[256 + tid] = reinterpret_cast<const int4*>(G)[256 + tid];
    __syncthreads();
    if (tid == 0) {
        int e = *best;
        E[255] = (unsigned char)e;
        for (int ch = 255; ch >= 1; --ch) { e = lG[ch * 32 + e]; E[ch - 1] = (unsigned char)e; }
    }
}
__global__ void bt_emit(const unsigned char* __restrict__ bp, const unsigned char* __restrict__ E,
                        float* __restrict__ out) {
    __shared__ unsigned char lbp[32][32];
    int c = blockIdx.x, tid = threadIdx.x;   // 64 threads
    reinterpret_cast<int4*>(lbp)[tid] = reinterpret_cast<const int4*>(bp + (size_t)c * 1024)[tid];
    __syncthreads();
    if (tid == 0) {
        int tag = E[c];
        for (int i = 31; i >= 0; --i) {
            out[1 + (size_t)c * 32 + i] = (float)tag;
            tag = lbp[i][tag];
        }
    }
}

// ---------------------------------------------------------------- launch
extern "C" void kernel_launch(void* const* d_in, const int* in_sizes, int n_in,
                              void* d_out, int out_size, void* d_ws, size_t ws_size,
                              hipStream_t stream)
{
    const int*   sentence = (const int*)d_in[0];
    const float* emb      = (const float*)d_in[1];
    const float* w_ih_f   = (const float*)d_in[2];
    const float* w_hh_f   = (const float*)d_in[3];
    const float* b_ih_f   = (const float*)d_in[4];
    const float* b_hh_f   = (const float*)d_in[5];
    const float* w_ih_r   = (const float*)d_in[6];
    const float* w_hh_r   = (const float*)d_in[7];
    const float* b_ih_r   = (const float*)d_in[8];
    const float* b_hh_r   = (const float*)d_in[9];
    const float* w_out    = (const float*)d_in[10];
    const float* b_out    = (const float*)d_in[11];
    const float* trans    = (const float*)d_in[12];
    (void)in_sizes; (void)n_in; (void)out_size; (void)ws_size;

    char* ws = (char*)d_ws;
    size_t off = 0;
    auto alloc = [&](size_t bytes) -> void* {
        void* p = (void*)(ws + off);
        off += (bytes + 255) & ~(size_t)255;
        return p;
    };
    float* gin_f   = (float*)alloc((size_t)SEQ * G4 * 4);          // 32 MiB
    float* gin_r   = (float*)alloc((size_t)SEQ * G4 * 4);          // 32 MiB
    float* hcomp_f = (float*)alloc((size_t)(SEQ + 1) * HD * 4);    // 8 MiB
    float* hcomp_r = (float*)alloc((size_t)(SEQ + 1) * HD * 4);    // 8 MiB
    float* wt_f    = (float*)alloc((size_t)EMBD * G4 * 4);         // 1 MiB
    float* wt_r    = (float*)alloc((size_t)EMBD * G4 * 4);         // 1 MiB
    float* bs_f    = (float*)alloc(G4 * 4);
    float* bs_r    = (float*)alloc(G4 * 4);
    unsigned* wq   = (unsigned*)alloc(2 * 65536 * 4);              // 512 KiB
    float* fac     = (float*)alloc(2 * 1024 * 4);
    float* feats   = (float*)alloc((size_t)SEQ * 32 * 4);          // 1 MiB
    unsigned char* bp = (unsigned char*)alloc((size_t)SEQ * 32);   // 256 KiB
    unsigned char* G  = (unsigned char*)alloc(256 * 32);           // 8 KiB
    unsigned char* E  = (unsigned char*)alloc(256);
    int* best_ws      = (int*)alloc(256);
    float* Pmat    = (float*)alloc((size_t)NCH * 1024 * 4);        // 1 MiB
    float* vbound  = (float*)alloc((size_t)NCH * 32 * 4);          // 32 KiB

    bias_kernel<<<1, 256, 0, stream>>>(b_ih_f, b_hh_f, b_ih_r, b_hh_r, bs_f, bs_r);
    wtrans_kernel<<<64, 256, 0, stream>>>(w_ih_f, w_ih_r, wt_f, wt_r);
    wquant_kernel<<<2048, 64, 0, stream>>>(w_hh_f, w_hh_r, wq, fac);
    gin_kernel<<<SEQ / 32, 256, 0, stream>>>(sentence, emb, wt_f, wt_r, bs_f, bs_r,
                                             gin_f, gin_r);
    lstm_kernel<<<2, 1024, 0, stream>>>(wq, fac, gin_f, gin_r, hcomp_f, hcomp_r);
    feats_kernel<<<SEQ / 256, 256, 0, stream>>>(hcomp_f, hcomp_r, w_out, b_out, feats);
    vp_chunks<<<NCH, 1024, 0, stream>>>(feats, trans, Pmat);
    vp_scan<<<1, 64, 0, stream>>>(Pmat, trans, vbound, (float*)d_out, best_ws);
    vp_replay<<<NCH, 64, 0, stream>>>(feats, trans, vbound, bp);
    bt_chunks<<<256, 64, 0, stream>>>(bp, G);
    bt_boundaries<<<1, 256, 0, stream>>>(G, best_ws, E);
    bt_emit<<<256, 64, 0, stream>>>(bp, E, (float*)d_out);
}

// Round 15
// 8586.114 us; speedup vs baseline: 1.8393x; 1.0398x over previous
//
#include <hip/hip_runtime.h>

// BiLSTM-CRF forward on MI355X.
//   bias:    bias sums.
//   wtrans:  LDS-tiled transpose of W_ih to [k][row].
//   wquant:  per-row int8 quantization of W_hh (quad-quarter layout).
//   gin:     embedding gather + input projection -> gin[t][rp] (rp=u*4+gate).
//   lstm:    2 blocks x 1024 threads (16 waves). R15: weight dwords PINNED to
//            arch VGPRs via empty-asm "+v" (R11-R13 allocated them to AGPRs —
//            VGPR_Count=48 signature — paying a suspected per-use accvgpr_read
//            on every v_dot4: ~64 extra VALU insts/step). Plus incremental
//            gin/hcomp pointer walk over a 2-step-padded gin buffer (kills the
//            per-step 64-bit mad + bounds select). LDS-only barrier (R13).
//   feats:   [hf,hr] @ w_out^T + b_out.
//   viterbi: max-plus chunk scan (vp_chunks/vp_scan/vp_replay, R14 proven)
//            + 3-phase parallel backtrace.

#define SEQ  8192
#define EMBD 256
#define HD   256
#define G4   1024
#define NEGV -10000.0f
#define NCH  256          // chunks
#define CLEN 32           // steps per chunk

#if __has_builtin(__builtin_amdgcn_sdot4)
__device__ __forceinline__ int SDOT4(unsigned a, unsigned b, int c) {
    return __builtin_amdgcn_sdot4((int)a, (int)b, c, false);
}
#else
__device__ __forceinline__ int SDOT4(unsigned a, unsigned b, int c) {
#pragma unroll
    for (int i = 0; i < 4; ++i) {
        int ai = (int)(a << (24 - 8 * i)) >> 24;
        int bi = (int)(b << (24 - 8 * i)) >> 24;
        c += ai * bi;
    }
    return c;
}
#endif

// LDS-only barrier: ds ops drained (h visibility), global ops stay in flight.
__device__ __forceinline__ void lds_barrier() {
    asm volatile("s_waitcnt lgkmcnt(0)\n\ts_barrier" ::: "memory");
}

// DPP quad_perm (VALU pipe)
template <int CTRL>
__device__ __forceinline__ float dpp_bcast(float x) {
    return __int_as_float(
        __builtin_amdgcn_mov_dpp(__float_as_int(x), CTRL, 0xf, 0xf, true));
}
template <int CTRL>
__device__ __forceinline__ int idpp(int x) {
    return __builtin_amdgcn_mov_dpp(x, CTRL, 0xf, 0xf, true);
}

__device__ __forceinline__ float bperm(int addr, float v) {
    return __int_as_float(__builtin_amdgcn_ds_bpermute(addr, __float_as_int(v)));
}

// pin 16 values into arch VGPRs (zero-cost if already there)
#define PIN16(a, o) asm volatile("" : "+v"(a[o+0]), "+v"(a[o+1]), "+v"(a[o+2]), \
    "+v"(a[o+3]), "+v"(a[o+4]), "+v"(a[o+5]), "+v"(a[o+6]), "+v"(a[o+7]),       \
    "+v"(a[o+8]), "+v"(a[o+9]), "+v"(a[o+10]), "+v"(a[o+11]), "+v"(a[o+12]),    \
    "+v"(a[o+13]), "+v"(a[o+14]), "+v"(a[o+15]))

// ---------------------------------------------------------------- bias sums
__global__ void bias_kernel(const float* __restrict__ b_ih_f, const float* __restrict__ b_hh_f,
                            const float* __restrict__ b_ih_r, const float* __restrict__ b_hh_r,
                            float* __restrict__ bs_f, float* __restrict__ bs_r) {
    int i = threadIdx.x;
#pragma unroll
    for (int m = 0; m < 4; ++m) {
        int row = i + 256 * m;
        bs_f[row] = b_ih_f[row] + b_hh_f[row];
        bs_r[row] = b_ih_r[row] + b_hh_r[row];
    }
}

// ---------------------------------------------------------------- W_ih transpose (tiled)
__global__ __launch_bounds__(256) void wtrans_kernel(
    const float* __restrict__ w_ih_f, const float* __restrict__ w_ih_r,
    float* __restrict__ wt_f, float* __restrict__ wt_r) {
    __shared__ float tile[32][257];
    int mat = blockIdx.x & 1;
    int r0  = (blockIdx.x >> 1) << 5;          // 0,32,...,992
    const float* src = mat ? w_ih_r : w_ih_f;
    float*       dst = mat ? wt_r   : wt_f;
    int tid = threadIdx.x;
    for (int r = 0; r < 32; ++r)
        tile[r][tid] = src[(size_t)(r0 + r) * EMBD + tid];
    __syncthreads();
    int row = tid & 31, kq = tid >> 5;
    for (int kb = 0; kb < EMBD; kb += 8) {
        int k = kb + kq;
        dst[(size_t)k * G4 + r0 + row] = tile[row][k];
    }
}

// ---------------------------------------------------------------- W_hh int8 quantization
// QUAD-QUARTER layout: wq[dir][(r*16+j)*1024 + u*4+g] = pack(W[row][g*64+4j ..]).
__global__ __launch_bounds__(64) void wquant_kernel(
    const float* __restrict__ w_hh_f, const float* __restrict__ w_hh_r,
    unsigned* __restrict__ wq, float* __restrict__ fac)
{
    int b = blockIdx.x;
    int dir = b >> 10, rp = b & 1023;
    int u = rp >> 2, r = rp & 3;
    int row = r * 256 + u;
    int l = threadIdx.x;
    int j = l & 15, g = l >> 4;
    const float* Wr = (dir ? w_hh_r : w_hh_f) + (size_t)row * HD;
    float4 v = reinterpret_cast<const float4*>(Wr)[g * 16 + j];   // k = g*64+4j
    float m = fmaxf(fmaxf(fabsf(v.x), fabsf(v.y)), fmaxf(fabsf(v.z), fabsf(v.w)));
#pragma unroll
    for (int off = 1; off < 64; off <<= 1) m = fmaxf(m, __shfl_xor(m, off));
    m = fmaxf(m, 1e-20f);
    float inv = 127.f / m;
    int q0 = (int)rintf(v.x * inv), q1 = (int)rintf(v.y * inv);
    int q2 = (int)rintf(v.z * inv), q3 = (int)rintf(v.w * inv);
    unsigned pk = (unsigned)(q0 & 0xff) | ((unsigned)(q1 & 0xff) << 8) |
                  ((unsigned)(q2 & 0xff) << 16) | ((unsigned)(q3 & 0xff) << 24);
    wq[(size_t)dir * 65536 + (size_t)(r * 16 + j) * 1024 + u * 4 + g] = pk;
    if (l == 0) fac[dir * 1024 + rp] = m / (127.f * 127.f);   // dequant scale
}

// ---------------------------------------------------------------- input projection
__global__ __launch_bounds__(256) void gin_kernel(
    const int* __restrict__ sentence, const float* __restrict__ emb,
    const float* __restrict__ wt_f, const float* __restrict__ wt_r,
    const float* __restrict__ bs_f, const float* __restrict__ bs_r,
    float* __restrict__ gin_f, float* __restrict__ gin_r)
{
    __shared__ float x_lds[32][EMBD];
    __shared__ int   sid_lds[32];
    int t0  = blockIdx.x * 32;
    int tid = threadIdx.x;
    if (tid < 32) sid_lds[tid] = sentence[t0 + tid];
    __syncthreads();
    for (int i = 0; i < 32; ++i)
        x_lds[i][tid] = emb[(size_t)sid_lds[i] * EMBD + tid];
    __syncthreads();

    float bsv[8];
#pragma unroll
    for (int m = 0; m < 4; ++m) bsv[m]     = bs_f[tid + 256 * m];
#pragma unroll
    for (int m = 0; m < 4; ++m) bsv[4 + m] = bs_r[tid + 256 * m];

    for (int tsub = 0; tsub < 4; ++tsub) {
        float acc[8][8];
#pragma unroll
        for (int m = 0; m < 8; ++m)
#pragma unroll
            for (int j = 0; j < 8; ++j) acc[m][j] = bsv[m];

        for (int k = 0; k < EMBD; ++k) {
            float xv[8];
#pragma unroll
            for (int j = 0; j < 8; ++j) xv[j] = x_lds[tsub * 8 + j][k];
#pragma unroll
            for (int m = 0; m < 8; ++m) {
                float wv = (m < 4) ? wt_f[(size_t)k * G4 + tid + 256 * m]
                                   : wt_r[(size_t)k * G4 + tid + 256 * (m - 4)];
#pragma unroll
                for (int j = 0; j < 8; ++j) acc[m][j] = fmaf(wv, xv[j], acc[m][j]);
            }
        }
#pragma unroll
        for (int m = 0; m < 8; ++m) {
            int rp = tid * 4 + (m & 3);        // u = tid, gate = m&3
#pragma unroll
            for (int j = 0; j < 8; ++j) {
                int t = t0 + tsub * 8 + j;
                if (m < 4) gin_f[(size_t)t * G4 + rp] = acc[m][j];
                else       gin_r[(size_t)(SEQ - 1 - t) * G4 + rp] = acc[m][j];
            }
        }
    }
}

// ---------------------------------------------------------------- single-CU LSTM per direction
// 2 blocks x 1024 threads (16 waves, 4/SIMD). Thread tid=(u=tid>>2, g=tid&3):
// holds quad u's 4 rows over k-quarter g (w[64] PINNED to arch VGPRs).
__global__ __launch_bounds__(1024, 4) void lstm_kernel(
    const unsigned* __restrict__ wq, const float* __restrict__ fac,
    const float* __restrict__ gin_f, const float* __restrict__ gin_r,
    float* __restrict__ hcomp_f, float* __restrict__ hcomp_r)
{
    int dir = blockIdx.x;
    const float* gin   = dir ? gin_r   : gin_f;
    float*       hcomp = dir ? hcomp_r : hcomp_f;
    int tid = threadIdx.x;
    int g   = tid & 3;
    int u   = tid >> 2;                        // 0..255
    bool q0 = (g == 0);

    unsigned w[64];                            // w[r*16+j]: row r, quarter-dword j
    {
        const unsigned* base = wq + (size_t)dir * 65536;
#pragma unroll
        for (int j = 0; j < 64; ++j) w[j] = base[(size_t)j * 1024 + tid];
    }
    // R15: pin weights into ARCH VGPRs (prevents AGPR allocation -> no
    // per-use accvgpr_read in the hot loop). Zero-cost if already VGPR.
    PIN16(w, 0); PIN16(w, 16); PIN16(w, 32); PIN16(w, 48);

    float4 fac4 = *reinterpret_cast<const float4*>(&fac[dir * 1024 + (u << 2)]);

    __shared__ unsigned hq[2][64];             // int8-packed h, double-buffered
    if (tid < 128) ((unsigned*)hq)[tid] = 0u;  // h(0) = 0 (both buffers)

    float aa = (g == 2) ? 2.f : 1.f;
    float bb = (g == 2) ? -2.f : -1.f;
    float cc = (g == 2) ? -1.f : 0.f;
    float c = 0.f;

    const float* gp = gin + tid;               // incremental walker
    float g0 = gp[0];
    float g1 = gp[G4];
    gp += 2 * (size_t)G4;                      // points at step t+2
    float* hc = hcomp + HD + u;                // h(t+1) slot walker
    __syncthreads();                           // once, pre-loop: full drain OK

    for (int t = 0; t < SEQ; ++t) {
        float g2 = *gp; gp += G4;              // unconditional: gin padded +2 steps

        const uint4* hb =
            reinterpret_cast<const uint4*>((const char*)hq[t & 1] + g * 64);
        uint4 h4[4];
#pragma unroll
        for (int i = 0; i < 4; ++i) h4[i] = hb[i];

        int s0 = 0, s1 = 0, s2 = 0, s3 = 0;    // partials for quad rows 0..3
#pragma unroll
        for (int i = 0; i < 4; ++i) {
            s0 = SDOT4(w[0 * 16 + 4 * i + 0], h4[i].x, s0);
            s1 = SDOT4(w[1 * 16 + 4 * i + 0], h4[i].x, s1);
            s2 = SDOT4(w[2 * 16 + 4 * i + 0], h4[i].x, s2);
            s3 = SDOT4(w[3 * 16 + 4 * i + 0], h4[i].x, s3);
            s0 = SDOT4(w[0 * 16 + 4 * i + 1], h4[i].y, s0);
            s1 = SDOT4(w[1 * 16 + 4 * i + 1], h4[i].y, s1);
            s2 = SDOT4(w[2 * 16 + 4 * i + 1], h4[i].y, s2);
            s3 = SDOT4(w[3 * 16 + 4 * i + 1], h4[i].y, s3);
            s0 = SDOT4(w[0 * 16 + 4 * i + 2], h4[i].z, s0);
            s1 = SDOT4(w[1 * 16 + 4 * i + 2], h4[i].z, s1);
            s2 = SDOT4(w[2 * 16 + 4 * i + 2], h4[i].z, s2);
            s3 = SDOT4(w[3 * 16 + 4 * i + 2], h4[i].z, s3);
            s0 = SDOT4(w[0 * 16 + 4 * i + 3], h4[i].w, s0);
            s1 = SDOT4(w[1 * 16 + 4 * i + 3], h4[i].w, s1);
            s2 = SDOT4(w[2 * 16 + 4 * i + 3], h4[i].w, s2);
            s3 = SDOT4(w[3 * 16 + 4 * i + 3], h4[i].w, s3);
        }
        int r0 = s0 + idpp<0xB1>(s0); r0 += idpp<0x4E>(r0);
        int r1 = s1 + idpp<0xB1>(s1); r1 += idpp<0x4E>(r1);
        int r2 = s2 + idpp<0xB1>(s2); r2 += idpp<0x4E>(r2);
        int r3 = s3 + idpp<0xB1>(s3); r3 += idpp<0x4E>(r3);

        int   ps = (g == 0) ? r0 : (g == 1) ? r1 : (g == 2) ? r2 : r3;
        float fs = (g == 0) ? fac4.x : (g == 1) ? fac4.y : (g == 2) ? fac4.z : fac4.w;

        float p   = fmaf((float)ps, fs, g0);
        float act = aa / (1.f + __expf(bb * p)) + cc;      // this row's gate act

        float xf = dpp_bcast<0x55>(act);       // f-gate (quad lane 1)
        float xg = dpp_bcast<0xAA>(act);       // g-gate (quad lane 2)
        float xo = dpp_bcast<0xFF>(act);       // o-gate (quad lane 3)

        if (q0) {                              // act = i; one lane per unit
            c = xf * c + act * xg;
            float h = xo * (2.f / (1.f + __expf(-2.f * c)) - 1.f);
            *hc = h;                           // fire-and-forget store
            ((char*)hq[(t + 1) & 1])[u] = (char)(int)rintf(h * 127.f);
        }
        hc += HD;
        lds_barrier();                         // LDS-only drain
        g0 = g1; g1 = g2;
    }
}

// ---------------------------------------------------------------- feats = [hf,hr] @ w_out^T + b
__global__ __launch_bounds__(256) void feats_kernel(
    const float* __restrict__ hf_buf, const float* __restrict__ hr_buf,
    const float* __restrict__ w_out, const float* __restrict__ b_out,
    float* __restrict__ feats)
{
    __shared__ __align__(16) float wt_lds[256][36];
    int tid = threadIdx.x;
    int t   = blockIdx.x * 256 + tid;

    float acc[32];
#pragma unroll
    for (int g = 0; g < 32; ++g) acc[g] = b_out[g];

    for (int half = 0; half < 2; ++half) {
        __syncthreads();
        for (int tag = 0; tag < 32; ++tag)
            wt_lds[tid][tag] = w_out[tag * 512 + half * 256 + tid];
        __syncthreads();

        const float* hsrc = (half == 0) ? &hf_buf[(size_t)(t + 1) * HD]
                                        : &hr_buf[(size_t)(SEQ - t) * HD];
        for (int k = 0; k < 256; k += 4) {
            float4 hv = *reinterpret_cast<const float4*>(&hsrc[k]);
#pragma unroll
            for (int kk = 0; kk < 4; ++kk) {
                float hx = (kk == 0) ? hv.x : (kk == 1) ? hv.y : (kk == 2) ? hv.z : hv.w;
#pragma unroll
                for (int qq = 0; qq < 8; ++qq) {
                    float4 wv = *reinterpret_cast<const float4*>(&wt_lds[k + kk][4 * qq]);
                    acc[4 * qq + 0] = fmaf(hx, wv.x, acc[4 * qq + 0]);
                    acc[4 * qq + 1] = fmaf(hx, wv.y, acc[4 * qq + 1]);
                    acc[4 * qq + 2] = fmaf(hx, wv.z, acc[4 * qq + 2]);
                    acc[4 * qq + 3] = fmaf(hx, wv.w, acc[4 * qq + 3]);
                }
            }
        }
    }
#pragma unroll
    for (int qq = 0; qq < 8; ++qq) {
        float4 o;
        o.x = acc[4 * qq + 0]; o.y = acc[4 * qq + 1];
        o.z = acc[4 * qq + 2]; o.w = acc[4 * qq + 3];
        *reinterpret_cast<float4*>(&feats[(size_t)t * 32 + 4 * qq]) = o;
    }
}

// ---------------------------------------------------------------- vp_chunks
__global__ __launch_bounds__(1024) void vp_chunks(
    const float* __restrict__ feats, const float* __restrict__ trans,
    float* __restrict__ Pmat)
{
    __shared__ float flds[CLEN * 32];
    int c = blockIdx.x, tid = threadIdx.x;
    flds[tid] = feats[(size_t)c * (CLEN * 32) + tid];
    __syncthreads();

    int l = tid & 63, w = tid >> 6;
    int n = l & 31, h = l >> 5;
    float Tn[16]; int addr[16];
#pragma unroll
    for (int j = 0; j < 16; ++j) {
        Tn[j]   = trans[n * 32 + 16 * h + j];
        addr[j] = (16 * h + j) * 4;
    }
    int pA = w, pB = w + 16;
    float vA = (n == pA) ? 0.f : -1e30f;       // basis columns (max-plus identity)
    float vB = (n == pB) ? 0.f : -1e30f;

    for (int s = 0; s < CLEN; ++s) {
        float fv = flds[s * 32 + n];
        float bA = -3.4e38f, bB = -3.4e38f;
#pragma unroll
        for (int j = 0; j < 16; ++j) {
            bA = fmaxf(bA, bperm(addr[j], vA) + Tn[j]);
            bB = fmaxf(bB, bperm(addr[j], vB) + Tn[j]);
        }
        bA = fmaxf(bA, __shfl_xor(bA, 32));
        bB = fmaxf(bB, __shfl_xor(bB, 32));
        vA = bA + fv;
        vB = bB + fv;
    }
    if (h == 0) {
        Pmat[(size_t)c * 1024 + n * 32 + pA] = vA;
        Pmat[(size_t)c * 1024 + n * 32 + pB] = vB;
    }
}

// ---------------------------------------------------------------- vp_scan
__global__ void vp_scan(const float* __restrict__ Pmat, const float* __restrict__ trans,
                        float* __restrict__ vbound, float* __restrict__ out,
                        int* __restrict__ best_ws)
{
    int l = threadIdx.x;
    int n = l & 31, h = l >> 5;
    int addr[16];
#pragma unroll
    for (int j = 0; j < 16; ++j) addr[j] = (16 * h + j) * 4;

    float vcur = (n == 30) ? 0.0f : NEGV;      // START = 30

    const float* Pr = Pmat + n * 32 + 16 * h;
    float4 nx0 = reinterpret_cast<const float4*>(Pr)[0];
    float4 nx1 = reinterpret_cast<const float4*>(Pr)[1];
    float4 nx2 = reinterpret_cast<const float4*>(Pr)[2];
    float4 nx3 = reinterpret_cast<const float4*>(Pr)[3];

    for (int c = 0; c < NCH; ++c) {
        float4 p0 = nx0, p1 = nx1, p2 = nx2, p3 = nx3;
        if (c + 1 < NCH) {
            const float* Pn = Pmat + (size_t)(c + 1) * 1024 + n * 32 + 16 * h;
            nx0 = reinterpret_cast<const float4*>(Pn)[0];
            nx1 = reinterpret_cast<const float4*>(Pn)[1];
            nx2 = reinterpret_cast<const float4*>(Pn)[2];
            nx3 = reinterpret_cast<const float4*>(Pn)[3];
        }
        if (h == 0) vbound[c * 32 + n] = vcur;  // v at chunk start

        float pr[16];
        *reinterpret_cast<float4*>(&pr[0])  = p0;
        *reinterpret_cast<float4*>(&pr[4])  = p1;
        *reinterpret_cast<float4*>(&pr[8])  = p2;
        *reinterpret_cast<float4*>(&pr[12]) = p3;

        float best = -3.4e38f;
#pragma unroll
        for (int j = 0; j < 16; ++j)
            best = fmaxf(best, bperm(addr[j], vcur) + pr[j]);
        best = fmaxf(best, __shfl_xor(best, 32));
        vcur = best;
    }

    float term = vcur + trans[31 * 32 + n];    // STOP = 31
    int idxv = n;
#pragma unroll
    for (int off = 1; off < 64; off <<= 1) {
        float ot = __shfl_xor(term, off);
        int   oi = __shfl_xor(idxv, off);
        if (ot > term || (ot == term && oi < idxv)) { term = ot; idxv = oi; }
    }
    if (l == 0) { out[0] = term; best_ws[0] = idxv; }
}

// ---------------------------------------------------------------- vp_replay
__global__ void vp_replay(const float* __restrict__ feats, const float* __restrict__ trans,
                          const float* __restrict__ vbound, unsigned char* __restrict__ bp)
{
    int c = blockIdx.x;
    int l = threadIdx.x;
    int n = l & 31, h = l >> 5;

    float Tn[16];
    int   addr[16], pidx[16];
#pragma unroll
    for (int j = 0; j < 16; ++j) {
        Tn[j]   = trans[n * 32 + 16 * h + j];
        addr[j] = (16 * h + j) * 4;
        pidx[j] = 16 * h + j;
    }

    float vcur = vbound[c * 32 + n];
    const float* fptr = feats + (size_t)c * (CLEN * 32) + n;
    float fnext = fptr[0];

    for (int s = 0; s < CLEN; ++s) {
        float fcur = fnext;
        if (s + 1 < CLEN) fnext = fptr[(size_t)(s + 1) * 32];

        float cand[16]; int idx[16];
#pragma unroll
        for (int j = 0; j < 16; ++j) {
            cand[j] = bperm(addr[j], vcur) + Tn[j];
            idx[j]  = pidx[j];
        }
#pragma unroll
        for (int st = 1; st < 16; st <<= 1)
#pragma unroll
            for (int p = 0; p < 16; p += 2 * st) {
                bool rgt = cand[p + st] > cand[p];   // left wins ties
                cand[p] = rgt ? cand[p + st] : cand[p];
                idx[p]  = rgt ? idx[p + st]  : idx[p];
            }
        float ob = __shfl_xor(cand[0], 32);
        int   oa = __shfl_xor(idx[0], 32);
        bool useOther = h ? (ob >= cand[0]) : (ob > cand[0]);  // low half wins ties
        float best = useOther ? ob : cand[0];
        int   aarg = useOther ? oa : idx[0];

        if (h == 0) bp[(size_t)(c * CLEN + s) * 32 + n] = (unsigned char)aarg;
        vcur = best + fcur;
    }
}

// ---------------------------------------------------------------- backtrace, 3 phases (proven)
__global__ void bt_chunks(const unsigned char* __restrict__ bp, unsigned char* __restrict__ G) {
    __shared__ unsigned char lbp[32][32];
    int c = blockIdx.x, tid = threadIdx.x;   // 64 threads
    reinterpret_cast<int4*>(lbp)[tid] = reinterpret_cast<const int4*>(bp + (size_t)c * 1024)[tid];
    __syncthreads();
    if (tid < 32) {
        int cur = tid;
#pragma unroll 8
        for (int i = 31; i >= 0; --i) cur = lbp[i][cur];
        G[c * 32 + tid] = (unsigned char)cur;
    }
}
__global__ void bt_boundaries(const unsigned char* __restrict__ G, const int* __restrict__ best,
                              unsigned char* __restrict__ E) {
    __shared__ unsigned char lG[256 * 32];
    int tid = threadIdx.x;                   // 256 threads
    reinterpret_cast<int4*>(lG)[tid]       = reinterpret_cast<const int4*>(G)[tid];
    reinterpret_cast<int4*>(lG)[256 + tid] = reinterpret_cast<const int4*>(G)[256 + tid];
    __syncthreads();
    if (tid == 0) {
        int e = *best;
        E[255] = (unsigned char)e;
        for (int ch = 255; ch >= 1; --ch) { e = lG[ch * 32 + e]; E[ch - 1] = (unsigned char)e; }
    }
}
__global__ void bt_emit(const unsigned char* __restrict__ bp, const unsigned char* __restrict__ E,
                        float* __restrict__ out) {
    __shared__ unsigned char lbp[32][32];
    int c = blockIdx.x, tid = threadIdx.x;   // 64 threads
    reinterpret_cast<int4*>(lbp)[tid] = reinterpret_cast<const int4*>(bp + (size_t)c * 1024)[tid];
    __syncthreads();
    if (tid == 0) {
        int tag = E[c];
        for (int i = 31; i >= 0; --i) {
            out[1 + (size_t)c * 32 + i] = (float)tag;
            tag = lbp[i][tag];
        }
    }
}

// ---------------------------------------------------------------- launch
extern "C" void kernel_launch(void* const* d_in, const int* in_sizes, int n_in,
                              void* d_out, int out_size, void* d_ws, size_t ws_size,
                              hipStream_t stream)
{
    const int*   sentence = (const int*)d_in[0];
    const float* emb      = (const float*)d_in[1];
    const float* w_ih_f   = (const float*)d_in[2];
    const float* w_hh_f   = (const float*)d_in[3];
    const float* b_ih_f   = (const float*)d_in[4];
    const float* b_hh_f   = (const float*)d_in[5];
    const float* w_ih_r   = (const float*)d_in[6];
    const float* w_hh_r   = (const float*)d_in[7];
    const float* b_ih_r   = (const float*)d_in[8];
    const float* b_hh_r   = (const float*)d_in[9];
    const float* w_out    = (const float*)d_in[10];
    const float* b_out    = (const float*)d_in[11];
    const float* trans    = (const float*)d_in[12];
    (void)in_sizes; (void)n_in; (void)out_size; (void)ws_size;

    char* ws = (char*)d_ws;
    size_t off = 0;
    auto alloc = [&](size_t bytes) -> void* {
        void* p = (void*)(ws + off);
        off += (bytes + 255) & ~(size_t)255;
        return p;
    };
    float* gin_f   = (float*)alloc((size_t)(SEQ + 2) * G4 * 4);    // 32 MiB (+2-step pad)
    float* gin_r   = (float*)alloc((size_t)(SEQ + 2) * G4 * 4);    // 32 MiB (+2-step pad)
    float* hcomp_f = (float*)alloc((size_t)(SEQ + 1) * HD * 4);    // 8 MiB
    float* hcomp_r = (float*)alloc((size_t)(SEQ + 1) * HD * 4);    // 8 MiB
    float* wt_f    = (float*)alloc((size_t)EMBD * G4 * 4);         // 1 MiB
    float* wt_r    = (float*)alloc((size_t)EMBD * G4 * 4);         // 1 MiB
    float* bs_f    = (float*)alloc(G4 * 4);
    float* bs_r    = (float*)alloc(G4 * 4);
    unsigned* wq   = (unsigned*)alloc(2 * 65536 * 4);              // 512 KiB
    float* fac     = (float*)alloc(2 * 1024 * 4);
    float* feats   = (float*)alloc((size_t)SEQ * 32 * 4);          // 1 MiB
    unsigned char* bp = (unsigned char*)alloc((size_t)SEQ * 32);   // 256 KiB
    unsigned char* G  = (unsigned char*)alloc(256 * 32);           // 8 KiB
    unsigned char* E  = (unsigned char*)alloc(256);
    int* best_ws      = (int*)alloc(256);
    float* Pmat    = (float*)alloc((size_t)NCH * 1024 * 4);        // 1 MiB
    float* vbound  = (float*)alloc((size_t)NCH * 32 * 4);          // 32 KiB

    bias_kernel<<<1, 256, 0, stream>>>(b_ih_f, b_hh_f, b_ih_r, b_hh_r, bs_f, bs_r);
    wtrans_kernel<<<64, 256, 0, stream>>>(w_ih_f, w_ih_r, wt_f, wt_r);
    wquant_kernel<<<2048, 64, 0, stream>>>(w_hh_f, w_hh_r, wq, fac);
    gin_kernel<<<SEQ / 32, 256, 0, stream>>>(sentence, emb, wt_f, wt_r, bs_f, bs_r,
                                             gin_f, gin_r);
    lstm_kernel<<<2, 1024, 0, stream>>>(wq, fac, gin_f, gin_r, hcomp_f, hcomp_r);
    feats_kernel<<<SEQ / 256, 256, 0, stream>>>(hcomp_f, hcomp_r, w_out, b_out, feats);
    vp_chunks<<<NCH, 1024, 0, stream>>>(feats, trans, Pmat);
    vp_scan<<<1, 64, 0, stream>>>(Pmat, trans, vbound, (float*)d_out, best_ws);
    vp_replay<<<NCH, 64, 0, stream>>>(feats, trans, vbound, bp);
    bt_chunks<<<256, 64, 0, stream>>>(bp, G);
    bt_boundaries<<<1, 256, 0, stream>>>(G, best_ws, E);
    bt_emit<<<256, 64, 0, stream>>>(bp, E, (float*)d_out);
}

// Round 16
// 7426.440 us; speedup vs baseline: 2.1265x; 1.1562x over previous
//
#include <hip/hip_runtime.h>

// BiLSTM-CRF forward on MI355X.
//   bias:    bias sums.
//   wtrans:  LDS-tiled transpose of W_ih to [k][row].
//   wquant:  per-row int8 quantization of W_hh (quad-quarter layout).
//   gin:     embedding gather + input projection -> gin[t][rp] (rp=u*4+gate).
//   lstm:    2 blocks x 1024 threads (16 waves). R16: (a) weights pinned to
//            arch VGPRs by empty-asm "v" inputs INSIDE the step loop (R15's
//            one-time pin was ignored by the allocator: VGPR_Count stayed 48 ->
//            suspected per-use v_accvgpr_read on every v_dot4); (b) sigmoid/
//            tanh via raw v_exp_f32(2^x) + v_rcp_f32 (drops __expf guard code).
//            LDS-only barrier, incremental pointers (R13/R15 proven).
//   feats:   [hf,hr] @ w_out^T + b_out.
//   viterbi: max-plus chunk scan (vp_chunks/vp_scan/vp_replay, R14 proven)
//            + 3-phase parallel backtrace.

#define SEQ  8192
#define EMBD 256
#define HD   256
#define G4   1024
#define NEGV -10000.0f
#define NCH  256          // chunks
#define CLEN 32           // steps per chunk

#if __has_builtin(__builtin_amdgcn_sdot4)
__device__ __forceinline__ int SDOT4(unsigned a, unsigned b, int c) {
    return __builtin_amdgcn_sdot4((int)a, (int)b, c, false);
}
#else
__device__ __forceinline__ int SDOT4(unsigned a, unsigned b, int c) {
#pragma unroll
    for (int i = 0; i < 4; ++i) {
        int ai = (int)(a << (24 - 8 * i)) >> 24;
        int bi = (int)(b << (24 - 8 * i)) >> 24;
        c += ai * bi;
    }
    return c;
}
#endif

// LDS-only barrier: ds ops drained (h visibility), global ops stay in flight.
__device__ __forceinline__ void lds_barrier() {
    asm volatile("s_waitcnt lgkmcnt(0)\n\ts_barrier" ::: "memory");
}

// DPP quad_perm (VALU pipe)
template <int CTRL>
__device__ __forceinline__ float dpp_bcast(float x) {
    return __int_as_float(
        __builtin_amdgcn_mov_dpp(__float_as_int(x), CTRL, 0xf, 0xf, true));
}
template <int CTRL>
__device__ __forceinline__ int idpp(int x) {
    return __builtin_amdgcn_mov_dpp(x, CTRL, 0xf, 0xf, true);
}

__device__ __forceinline__ float bperm(int addr, float v) {
    return __int_as_float(__builtin_amdgcn_ds_bpermute(addr, __float_as_int(v)));
}

// raw transcendentals: v_exp_f32 computes 2^x; v_rcp_f32 ~1ulp reciprocal
__device__ __forceinline__ float fexp2(float x) {
    float r; asm("v_exp_f32 %0, %1" : "=v"(r) : "v"(x)); return r;
}
__device__ __forceinline__ float frcp(float x) {
    float r; asm("v_rcp_f32 %0, %1" : "=v"(r) : "v"(x)); return r;
}

// force 16 values into arch VGPRs at this program point (input-only, no copy-back)
#define PINV16(a, o) asm volatile("" :: "v"(a[o+0]), "v"(a[o+1]), "v"(a[o+2]),  \
    "v"(a[o+3]), "v"(a[o+4]), "v"(a[o+5]), "v"(a[o+6]), "v"(a[o+7]),            \
    "v"(a[o+8]), "v"(a[o+9]), "v"(a[o+10]), "v"(a[o+11]), "v"(a[o+12]),         \
    "v"(a[o+13]), "v"(a[o+14]), "v"(a[o+15]))

// ---------------------------------------------------------------- bias sums
__global__ void bias_kernel(const float* __restrict__ b_ih_f, const float* __restrict__ b_hh_f,
                            const float* __restrict__ b_ih_r, const float* __restrict__ b_hh_r,
                            float* __restrict__ bs_f, float* __restrict__ bs_r) {
    int i = threadIdx.x;
#pragma unroll
    for (int m = 0; m < 4; ++m) {
        int row = i + 256 * m;
        bs_f[row] = b_ih_f[row] + b_hh_f[row];
        bs_r[row] = b_ih_r[row] + b_hh_r[row];
    }
}

// ---------------------------------------------------------------- W_ih transpose (tiled)
__global__ __launch_bounds__(256) void wtrans_kernel(
    const float* __restrict__ w_ih_f, const float* __restrict__ w_ih_r,
    float* __restrict__ wt_f, float* __restrict__ wt_r) {
    __shared__ float tile[32][257];
    int mat = blockIdx.x & 1;
    int r0  = (blockIdx.x >> 1) << 5;          // 0,32,...,992
    const float* src = mat ? w_ih_r : w_ih_f;
    float*       dst = mat ? wt_r   : wt_f;
    int tid = threadIdx.x;
    for (int r = 0; r < 32; ++r)
        tile[r][tid] = src[(size_t)(r0 + r) * EMBD + tid];
    __syncthreads();
    int row = tid & 31, kq = tid >> 5;
    for (int kb = 0; kb < EMBD; kb += 8) {
        int k = kb + kq;
        dst[(size_t)k * G4 + r0 + row] = tile[row][k];
    }
}

// ---------------------------------------------------------------- W_hh int8 quantization
// QUAD-QUARTER layout: wq[dir][(r*16+j)*1024 + u*4+g] = pack(W[row][g*64+4j ..]).
__global__ __launch_bounds__(64) void wquant_kernel(
    const float* __restrict__ w_hh_f, const float* __restrict__ w_hh_r,
    unsigned* __restrict__ wq, float* __restrict__ fac)
{
    int b = blockIdx.x;
    int dir = b >> 10, rp = b & 1023;
    int u = rp >> 2, r = rp & 3;
    int row = r * 256 + u;
    int l = threadIdx.x;
    int j = l & 15, g = l >> 4;
    const float* Wr = (dir ? w_hh_r : w_hh_f) + (size_t)row * HD;
    float4 v = reinterpret_cast<const float4*>(Wr)[g * 16 + j];   // k = g*64+4j
    float m = fmaxf(fmaxf(fabsf(v.x), fabsf(v.y)), fmaxf(fabsf(v.z), fabsf(v.w)));
#pragma unroll
    for (int off = 1; off < 64; off <<= 1) m = fmaxf(m, __shfl_xor(m, off));
    m = fmaxf(m, 1e-20f);
    float inv = 127.f / m;
    int q0 = (int)rintf(v.x * inv), q1 = (int)rintf(v.y * inv);
    int q2 = (int)rintf(v.z * inv), q3 = (int)rintf(v.w * inv);
    unsigned pk = (unsigned)(q0 & 0xff) | ((unsigned)(q1 & 0xff) << 8) |
                  ((unsigned)(q2 & 0xff) << 16) | ((unsigned)(q3 & 0xff) << 24);
    wq[(size_t)dir * 65536 + (size_t)(r * 16 + j) * 1024 + u * 4 + g] = pk;
    if (l == 0) fac[dir * 1024 + rp] = m / (127.f * 127.f);   // dequant scale
}

// ---------------------------------------------------------------- input projection
__global__ __launch_bounds__(256) void gin_kernel(
    const int* __restrict__ sentence, const float* __restrict__ emb,
    const float* __restrict__ wt_f, const float* __restrict__ wt_r,
    const float* __restrict__ bs_f, const float* __restrict__ bs_r,
    float* __restrict__ gin_f, float* __restrict__ gin_r)
{
    __shared__ float x_lds[32][EMBD];
    __shared__ int   sid_lds[32];
    int t0  = blockIdx.x * 32;
    int tid = threadIdx.x;
    if (tid < 32) sid_lds[tid] = sentence[t0 + tid];
    __syncthreads();
    for (int i = 0; i < 32; ++i)
        x_lds[i][tid] = emb[(size_t)sid_lds[i] * EMBD + tid];
    __syncthreads();

    float bsv[8];
#pragma unroll
    for (int m = 0; m < 4; ++m) bsv[m]     = bs_f[tid + 256 * m];
#pragma unroll
    for (int m = 0; m < 4; ++m) bsv[4 + m] = bs_r[tid + 256 * m];

    for (int tsub = 0; tsub < 4; ++tsub) {
        float acc[8][8];
#pragma unroll
        for (int m = 0; m < 8; ++m)
#pragma unroll
            for (int j = 0; j < 8; ++j) acc[m][j] = bsv[m];

        for (int k = 0; k < EMBD; ++k) {
            float xv[8];
#pragma unroll
            for (int j = 0; j < 8; ++j) xv[j] = x_lds[tsub * 8 + j][k];
#pragma unroll
            for (int m = 0; m < 8; ++m) {
                float wv = (m < 4) ? wt_f[(size_t)k * G4 + tid + 256 * m]
                                   : wt_r[(size_t)k * G4 + tid + 256 * (m - 4)];
#pragma unroll
                for (int j = 0; j < 8; ++j) acc[m][j] = fmaf(wv, xv[j], acc[m][j]);
            }
        }
#pragma unroll
        for (int m = 0; m < 8; ++m) {
            int rp = tid * 4 + (m & 3);        // u = tid, gate = m&3
#pragma unroll
            for (int j = 0; j < 8; ++j) {
                int t = t0 + tsub * 8 + j;
                if (m < 4) gin_f[(size_t)t * G4 + rp] = acc[m][j];
                else       gin_r[(size_t)(SEQ - 1 - t) * G4 + rp] = acc[m][j];
            }
        }
    }
}

// ---------------------------------------------------------------- single-CU LSTM per direction
// 2 blocks x 1024 threads (16 waves, 4/SIMD). Thread tid=(u=tid>>2, g=tid&3):
// holds quad u's 4 rows over k-quarter g; w[64] pinned per-iteration to VGPRs.
__global__ __launch_bounds__(1024, 4) void lstm_kernel(
    const unsigned* __restrict__ wq, const float* __restrict__ fac,
    const float* __restrict__ gin_f, const float* __restrict__ gin_r,
    float* __restrict__ hcomp_f, float* __restrict__ hcomp_r)
{
    int dir = blockIdx.x;
    const float* gin   = dir ? gin_r   : gin_f;
    float*       hcomp = dir ? hcomp_r : hcomp_f;
    int tid = threadIdx.x;
    int g   = tid & 3;
    int u   = tid >> 2;                        // 0..255
    bool q0 = (g == 0);

    unsigned w[64];                            // w[r*16+j]: row r, quarter-dword j
    {
        const unsigned* base = wq + (size_t)dir * 65536;
#pragma unroll
        for (int j = 0; j < 64; ++j) w[j] = base[(size_t)j * 1024 + tid];
    }

    float4 fac4 = *reinterpret_cast<const float4*>(&fac[dir * 1024 + (u << 2)]);

    __shared__ unsigned hq[2][64];             // int8-packed h, double-buffered
    if (tid < 128) ((unsigned*)hq)[tid] = 0u;  // h(0) = 0 (both buffers)

    // per-gate activation via native 2^x: act = aa * rcp(1 + 2^(bbl*p)) + cc
    const float LOG2E = 1.44269504f;
    float aa  = (g == 2) ? 2.f : 1.f;
    float bbl = (g == 2) ? (-2.f * LOG2E) : (-LOG2E);
    float cc  = (g == 2) ? -1.f : 0.f;
    float c = 0.f;

    const float* gp = gin + tid;               // incremental walker
    float g0 = gp[0];
    float g1 = gp[G4];
    gp += 2 * (size_t)G4;                      // points at step t+2
    float* hc = hcomp + HD + u;                // h(t+1) slot walker
    __syncthreads();                           // once, pre-loop: full drain OK

    for (int t = 0; t < SEQ; ++t) {
        float g2 = *gp; gp += G4;              // unconditional: gin padded +2 steps

        const uint4* hb =
            reinterpret_cast<const uint4*>((const char*)hq[t & 1] + g * 64);
        uint4 h4[4];
#pragma unroll
        for (int i = 0; i < 4; ++i) h4[i] = hb[i];

        // R16: pin all 64 weight dwords into ARCH VGPRs at a point inside the
        // hot loop -> allocator keeps them VGPR-resident (no per-use
        // accvgpr_read before each v_dot4). Zero instructions if already VGPR.
        PINV16(w, 0); PINV16(w, 16); PINV16(w, 32); PINV16(w, 48);

        int s0 = 0, s1 = 0, s2 = 0, s3 = 0;    // partials for quad rows 0..3
#pragma unroll
        for (int i = 0; i < 4; ++i) {
            s0 = SDOT4(w[0 * 16 + 4 * i + 0], h4[i].x, s0);
            s1 = SDOT4(w[1 * 16 + 4 * i + 0], h4[i].x, s1);
            s2 = SDOT4(w[2 * 16 + 4 * i + 0], h4[i].x, s2);
            s3 = SDOT4(w[3 * 16 + 4 * i + 0], h4[i].x, s3);
            s0 = SDOT4(w[0 * 16 + 4 * i + 1], h4[i].y, s0);
            s1 = SDOT4(w[1 * 16 + 4 * i + 1], h4[i].y, s1);
            s2 = SDOT4(w[2 * 16 + 4 * i + 1], h4[i].y, s2);
            s3 = SDOT4(w[3 * 16 + 4 * i + 1], h4[i].y, s3);
            s0 = SDOT4(w[0 * 16 + 4 * i + 2], h4[i].z, s0);
            s1 = SDOT4(w[1 * 16 + 4 * i + 2], h4[i].z, s1);
            s2 = SDOT4(w[2 * 16 + 4 * i + 2], h4[i].z, s2);
            s3 = SDOT4(w[3 * 16 + 4 * i + 2], h4[i].z, s3);
            s0 = SDOT4(w[0 * 16 + 4 * i + 3], h4[i].w, s0);
            s1 = SDOT4(w[1 * 16 + 4 * i + 3], h4[i].w, s1);
            s2 = SDOT4(w[2 * 16 + 4 * i + 3], h4[i].w, s2);
            s3 = SDOT4(w[3 * 16 + 4 * i + 3], h4[i].w, s3);
        }
        int r0 = s0 + idpp<0xB1>(s0); r0 += idpp<0x4E>(r0);
        int r1 = s1 + idpp<0xB1>(s1); r1 += idpp<0x4E>(r1);
        int r2 = s2 + idpp<0xB1>(s2); r2 += idpp<0x4E>(r2);
        int r3 = s3 + idpp<0xB1>(s3); r3 += idpp<0x4E>(r3);

        int   ps = (g == 0) ? r0 : (g == 1) ? r1 : (g == 2) ? r2 : r3;
        float fs = (g == 0) ? fac4.x : (g == 1) ? fac4.y : (g == 2) ? fac4.z : fac4.w;

        float p   = fmaf((float)ps, fs, g0);
        float act = fmaf(aa, frcp(1.f + fexp2(bbl * p)), cc);  // this row's gate act

        float xf = dpp_bcast<0x55>(act);       // f-gate (quad lane 1)
        float xg = dpp_bcast<0xAA>(act);       // g-gate (quad lane 2)
        float xo = dpp_bcast<0xFF>(act);       // o-gate (quad lane 3)

        if (q0) {                              // act = i; one lane per unit
            c = xf * c + act * xg;
            float th = fmaf(2.f, frcp(1.f + fexp2(-2.f * LOG2E * c)), -1.f);
            float h = xo * th;
            *hc = h;                           // fire-and-forget store
            ((char*)hq[(t + 1) & 1])[u] = (char)(int)rintf(h * 127.f);
        }
        hc += HD;
        lds_barrier();                         // LDS-only drain
        g0 = g1; g1 = g2;
    }
}

// ---------------------------------------------------------------- feats = [hf,hr] @ w_out^T + b
__global__ __launch_bounds__(256) void feats_kernel(
    const float* __restrict__ hf_buf, const float* __restrict__ hr_buf,
    const float* __restrict__ w_out, const float* __restrict__ b_out,
    float* __restrict__ feats)
{
    __shared__ __align__(16) float wt_lds[256][36];
    int tid = threadIdx.x;
    int t   = blockIdx.x * 256 + tid;

    float acc[32];
#pragma unroll
    for (int g = 0; g < 32; ++g) acc[g] = b_out[g];

    for (int half = 0; half < 2; ++half) {
        __syncthreads();
        for (int tag = 0; tag < 32; ++tag)
            wt_lds[tid][tag] = w_out[tag * 512 + half * 256 + tid];
        __syncthreads();

        const float* hsrc = (half == 0) ? &hf_buf[(size_t)(t + 1) * HD]
                                        : &hr_buf[(size_t)(SEQ - t) * HD];
        for (int k = 0; k < 256; k += 4) {
            float4 hv = *reinterpret_cast<const float4*>(&hsrc[k]);
#pragma unroll
            for (int kk = 0; kk < 4; ++kk) {
                float hx = (kk == 0) ? hv.x : (kk == 1) ? hv.y : (kk == 2) ? hv.z : hv.w;
#pragma unroll
                for (int qq = 0; qq < 8; ++qq) {
                    float4 wv = *reinterpret_cast<const float4*>(&wt_lds[k + kk][4 * qq]);
                    acc[4 * qq + 0] = fmaf(hx, wv.x, acc[4 * qq + 0]);
                    acc[4 * qq + 1] = fmaf(hx, wv.y, acc[4 * qq + 1]);
                    acc[4 * qq + 2] = fmaf(hx, wv.z, acc[4 * qq + 2]);
                    acc[4 * qq + 3] = fmaf(hx, wv.w, acc[4 * qq + 3]);
                }
            }
        }
    }
#pragma unroll
    for (int qq = 0; qq < 8; ++qq) {
        float4 o;
        o.x = acc[4 * qq + 0]; o.y = acc[4 * qq + 1];
        o.z = acc[4 * qq + 2]; o.w = acc[4 * qq + 3];
        *reinterpret_cast<float4*>(&feats[(size_t)t * 32 + 4 * qq]) = o;
    }
}

// ---------------------------------------------------------------- vp_chunks
__global__ __launch_bounds__(1024) void vp_chunks(
    const float* __restrict__ feats, const float* __restrict__ trans,
    float* __restrict__ Pmat)
{
    __shared__ float flds[CLEN * 32];
    int c = blockIdx.x, tid = threadIdx.x;
    flds[tid] = feats[(size_t)c * (CLEN * 32) + tid];
    __syncthreads();

    int l = tid & 63, w = tid >> 6;
    int n = l & 31, h = l >> 5;
    float Tn[16]; int addr[16];
#pragma unroll
    for (int j = 0; j < 16; ++j) {
        Tn[j]   = trans[n * 32 + 16 * h + j];
        addr[j] = (16 * h + j) * 4;
    }
    int pA = w, pB = w + 16;
    float vA = (n == pA) ? 0.f : -1e30f;       // basis columns (max-plus identity)
    float vB = (n == pB) ? 0.f : -1e30f;

    for (int s = 0; s < CLEN; ++s) {
        float fv = flds[s * 32 + n];
        float bA = -3.4e38f, bB = -3.4e38f;
#pragma unroll
        for (int j = 0; j < 16; ++j) {
            bA = fmaxf(bA, bperm(addr[j], vA) + Tn[j]);
            bB = fmaxf(bB, bperm(addr[j], vB) + Tn[j]);
        }
        bA = fmaxf(bA, __shfl_xor(bA, 32));
        bB = fmaxf(bB, __shfl_xor(bB, 32));
        vA = bA + fv;
        vB = bB + fv;
    }
    if (h == 0) {
        Pmat[(size_t)c * 1024 + n * 32 + pA] = vA;
        Pmat[(size_t)c * 1024 + n * 32 + pB] = vB;
    }
}

// ---------------------------------------------------------------- vp_scan
__global__ void vp_scan(const float* __restrict__ Pmat, const float* __restrict__ trans,
                        float* __restrict__ vbound, float* __restrict__ out,
                        int* __restrict__ best_ws)
{
    int l = threadIdx.x;
    int n = l & 31, h = l >> 5;
    int addr[16];
#pragma unroll
    for (int j = 0; j < 16; ++j) addr[j] = (16 * h + j) * 4;

    float vcur = (n == 30) ? 0.0f : NEGV;      // START = 30

    const float* Pr = Pmat + n * 32 + 16 * h;
    float4 nx0 = reinterpret_cast<const float4*>(Pr)[0];
    float4 nx1 = reinterpret_cast<const float4*>(Pr)[1];
    float4 nx2 = reinterpret_cast<const float4*>(Pr)[2];
    float4 nx3 = reinterpret_cast<const float4*>(Pr)[3];

    for (int c = 0; c < NCH; ++c) {
        float4 p0 = nx0, p1 = nx1, p2 = nx2, p3 = nx3;
        if (c + 1 < NCH) {
            const float* Pn = Pmat + (size_t)(c + 1) * 1024 + n * 32 + 16 * h;
            nx0 = reinterpret_cast<const float4*>(Pn)[0];
            nx1 = reinterpret_cast<const float4*>(Pn)[1];
            nx2 = reinterpret_cast<const float4*>(Pn)[2];
            nx3 = reinterpret_cast<const float4*>(Pn)[3];
        }
        if (h == 0) vbound[c * 32 + n] = vcur;  // v at chunk start

        float pr[16];
        *reinterpret_cast<float4*>(&pr[0])  = p0;
        *reinterpret_cast<float4*>(&pr[4])  = p1;
        *reinterpret_cast<float4*>(&pr[8])  = p2;
        *reinterpret_cast<float4*>(&pr[12]) = p3;

        float best = -3.4e38f;
#pragma unroll
        for (int j = 0; j < 16; ++j)
            best = fmaxf(best, bperm(addr[j], vcur) + pr[j]);
        best = fmaxf(best, __shfl_xor(best, 32));
        vcur = best;
    }

    float term = vcur + trans[31 * 32 + n];    // STOP = 31
    int idxv = n;
#pragma unroll
    for (int off = 1; off < 64; off <<= 1) {
        float ot = __shfl_xor(term, off);
        int   oi = __shfl_xor(idxv, off);
        if (ot > term || (ot == term && oi < idxv)) { term = ot; idxv = oi; }
    }
    if (l == 0) { out[0] = term; best_ws[0] = idxv; }
}

// ---------------------------------------------------------------- vp_replay
__global__ void vp_replay(const float* __restrict__ feats, const float* __restrict__ trans,
                          const float* __restrict__ vbound, unsigned char* __restrict__ bp)
{
    int c = blockIdx.x;
    int l = threadIdx.x;
    int n = l & 31, h = l >> 5;

    float Tn[16];
    int   addr[16], pidx[16];
#pragma unroll
    for (int j = 0; j < 16; ++j) {
        Tn[j]   = trans[n * 32 + 16 * h + j];
        addr[j] = (16 * h + j) * 4;
        pidx[j] = 16 * h + j;
    }

    float vcur = vbound[c * 32 + n];
    const float* fptr = feats + (size_t)c * (CLEN * 32) + n;
    float fnext = fptr[0];

    for (int s = 0; s < CLEN; ++s) {
        float fcur = fnext;
        if (s + 1 < CLEN) fnext = fptr[(size_t)(s + 1) * 32];

        float cand[16]; int idx[16];
#pragma unroll
        for (int j = 0; j < 16; ++j) {
            cand[j] = bperm(addr[j], vcur) + Tn[j];
            idx[j]  = pidx[j];
        }
#pragma unroll
        for (int st = 1; st < 16; st <<= 1)
#pragma unroll
            for (int p = 0; p < 16; p += 2 * st) {
                bool rgt = cand[p + st] > cand[p];   // left wins ties
                cand[p] = rgt ? cand[p + st] : cand[p];
                idx[p]  = rgt ? idx[p + st]  : idx[p];
            }
        float ob = __shfl_xor(cand[0], 32);
        int   oa = __shfl_xor(idx[0], 32);
        bool useOther = h ? (ob >= cand[0]) : (ob > cand[0]);  // low half wins ties
        float best = useOther ? ob : cand[0];
        int   aarg = useOther ? oa : idx[0];

        if (h == 0) bp[(size_t)(c * CLEN + s) * 32 + n] = (unsigned char)aarg;
        vcur = best + fcur;
    }
}

// ---------------------------------------------------------------- backtrace, 3 phases (proven)
__global__ void bt_chunks(const unsigned char* __restrict__ bp, unsigned char* __restrict__ G) {
    __shared__ unsigned char lbp[32][32];
    int c = blockIdx.x, tid = threadIdx.x;   // 64 threads
    reinterpret_cast<int4*>(lbp)[tid] = reinterpret_cast<const int4*>(bp + (size_t)c * 1024)[tid];
    __syncthreads();
    if (tid < 32) {
        int cur = tid;
#pragma unroll 8
        for (int i = 31; i >= 0; --i) cur = lbp[i][cur];
        G[c * 32 + tid] = (unsigned char)cur;
    }
}
__global__ void bt_boundaries(const unsigned char* __restrict__ G, const int* __restrict__ best,
                              unsigned char* __restrict__ E) {
    __shared__ unsigned char lG[256 * 32];
    int tid = threadIdx.x;                   // 256 threads
    reinterpret_cast<int4*>(lG)[tid]       = reinterpret_cast<const int4*>(G)[tid];
    reinterpret_cast<int4*>(lG)[256 + tid] = reinterpret_cast<const int4*>(G)[256 + tid];
    __syncthreads();
    if (tid == 0) {
        int e = *best;
        E[255] = (unsigned char)e;
        for (int ch = 255; ch >= 1; --ch) { e = lG[ch * 32 + e]; E[ch - 1] = (unsigned char)e; }
    }
}
__global__ void bt_emit(const unsigned char* __restrict__ bp, const unsigned char* __restrict__ E,
                        float* __restrict__ out) {
    __shared__ unsigned char lbp[32][32];
    int c = blockIdx.x, tid = threadIdx.x;   // 64 threads
    reinterpret_cast<int4*>(lbp)[tid] = reinterpret_cast<const int4*>(bp + (size_t)c * 1024)[tid];
    __syncthreads();
    if (tid == 0) {
        int tag = E[c];
        for (int i = 31; i >= 0; --i) {
            out[1 + (size_t)c * 32 + i] = (float)tag;
            tag = lbp[i][tag];
        }
    }
}

// ---------------------------------------------------------------- launch
extern "C" void kernel_launch(void* const* d_in, const int* in_sizes, int n_in,
                              void* d_out, int out_size, void* d_ws, size_t ws_size,
                              hipStream_t stream)
{
    const int*   sentence = (const int*)d_in[0];
    const float* emb      = (const float*)d_in[1];
    const float* w_ih_f   = (const float*)d_in[2];
    const float* w_hh_f   = (const float*)d_in[3];
    const float* b_ih_f   = (const float*)d_in[4];
    const float* b_hh_f   = (const float*)d_in[5];
    const float* w_ih_r   = (const float*)d_in[6];
    const float* w_hh_r   = (const float*)d_in[7];
    const float* b_ih_r   = (const float*)d_in[8];
    const float* b_hh_r   = (const float*)d_in[9];
    const float* w_out    = (const float*)d_in[10];
    const float* b_out    = (const float*)d_in[11];
    const float* trans    = (const float*)d_in[12];
    (void)in_sizes; (void)n_in; (void)out_size; (void)ws_size;

    char* ws = (char*)d_ws;
    size_t off = 0;
    auto alloc = [&](size_t bytes) -> void* {
        void* p = (void*)(ws + off);
        off += (bytes + 255) & ~(size_t)255;
        return p;
    };
    float* gin_f   = (float*)alloc((size_t)(SEQ + 2) * G4 * 4);    // 32 MiB (+2-step pad)
    float* gin_r   = (float*)alloc((size_t)(SEQ + 2) * G4 * 4);    // 32 MiB (+2-step pad)
    float* hcomp_f = (float*)alloc((size_t)(SEQ + 1) * HD * 4);    // 8 MiB
    float* hcomp_r = (float*)alloc((size_t)(SEQ + 1) * HD * 4);    // 8 MiB
    float* wt_f    = (float*)alloc((size_t)EMBD * G4 * 4);         // 1 MiB
    float* wt_r    = (float*)alloc((size_t)EMBD * G4 * 4);         // 1 MiB
    float* bs_f    = (float*)alloc(G4 * 4);
    float* bs_r    = (float*)alloc(G4 * 4);
    unsigned* wq   = (unsigned*)alloc(2 * 65536 * 4);              // 512 KiB
    float* fac     = (float*)alloc(2 * 1024 * 4);
    float* feats   = (float*)alloc((size_t)SEQ * 32 * 4);          // 1 MiB
    unsigned char* bp = (unsigned char*)alloc((size_t)SEQ * 32);   // 256 KiB
    unsigned char* G  = (unsigned char*)alloc(256 * 32);           // 8 KiB
    unsigned char* E  = (unsigned char*)alloc(256);
    int* best_ws      = (int*)alloc(256);
    float* Pmat    = (float*)alloc((size_t)NCH * 1024 * 4);        // 1 MiB
    float* vbound  = (float*)alloc((size_t)NCH * 32 * 4);          // 32 KiB

    bias_kernel<<<1, 256, 0, stream>>>(b_ih_f, b_hh_f, b_ih_r, b_hh_r, bs_f, bs_r);
    wtrans_kernel<<<64, 256, 0, stream>>>(w_ih_f, w_ih_r, wt_f, wt_r);
    wquant_kernel<<<2048, 64, 0, stream>>>(w_hh_f, w_hh_r, wq, fac);
    gin_kernel<<<SEQ / 32, 256, 0, stream>>>(sentence, emb, wt_f, wt_r, bs_f, bs_r,
                                             gin_f, gin_r);
    lstm_kernel<<<2, 1024, 0, stream>>>(wq, fac, gin_f, gin_r, hcomp_f, hcomp_r);
    feats_kernel<<<SEQ / 256, 256, 0, stream>>>(hcomp_f, hcomp_r, w_out, b_out, feats);
    vp_chunks<<<NCH, 1024, 0, stream>>>(feats, trans, Pmat);
    vp_scan<<<1, 64, 0, stream>>>(Pmat, trans, vbound, (float*)d_out, best_ws);
    vp_replay<<<NCH, 64, 0, stream>>>(feats, trans, vbound, bp);
    bt_chunks<<<256, 64, 0, stream>>>(bp, G);
    bt_boundaries<<<1, 256, 0, stream>>>(G, best_ws, E);
    bt_emit<<<256, 64, 0, stream>>>(bp, E, (float*)d_out);
}